// Round 6
// baseline (569.252 us; speedup 1.0000x reference)
//
#include <hip/hip_runtime.h>
#include <math.h>

#define EPS 1e-5f
#define PS 8  // pool slices per group

typedef __attribute__((ext_vector_type(8))) short short8;
typedef __attribute__((ext_vector_type(4))) float f32x4;

__device__ __forceinline__ float bflo(unsigned u) {
  union { unsigned i; float f; } c; c.i = u << 16; return c.f;
}
__device__ __forceinline__ float bfhi(unsigned u) {
  union { unsigned i; float f; } c; c.i = u & 0xFFFF0000u; return c.f;
}
__device__ __forceinline__ unsigned short f2bf(float f) {
  union { float f; unsigned i; } c; c.f = f;
  unsigned r = c.i + 0x7FFF + ((c.i >> 16) & 1);
  return (unsigned short)(r >> 16);
}

// ---------------------------------------------------------------------------
// Fused GEMM + epilogue. BM=64 rows/block for occupancy (782 blocks).
// 256 thr = 4 waves (2 wm x 2 wn), wave tile 32x64, 16x16x32 bf16 MFMA.
// MODE 0 (embed): h = relu(x_f32 @ W^T + bias); writes h fp32 + hb bf16;
//                 optional scores = h @ Wsc + bsc.
// MODE 1 (layer): z = [hb | uv] @ W^T + bias (K=384); LayerNorm; relu;
//                 += h residual; writes h fp32 + hb bf16; optional score.
// Row stats cross-wave reduction via LDS ([64][2] planes).
// ---------------------------------------------------------------------------
template <int MODE, bool SCORE>
__global__ __launch_bounds__(256) void fused_gemm(
    const float* __restrict__ Axf,    // MODE 0: x fp32 [M][128]
    const ushort* __restrict__ A0,    // MODE 1: hb [M][128] bf16
    const ushort* __restrict__ A1,    // MODE 1: uv [M][256] bf16
    const ushort* __restrict__ W,     // [128][K] bf16
    const float* __restrict__ bias,   // [128]
    const float* __restrict__ gamma,  // MODE 1
    const float* __restrict__ beta,   // MODE 1
    const float* __restrict__ Wsc,    // SCORE
    const float* __restrict__ bsc,    // SCORE
    float* __restrict__ h,            // state fp32 (MODE1: read residual + write)
    ushort* __restrict__ hb,          // state bf16
    float* __restrict__ scores, int M) {
  constexpr int KT = (MODE == 0) ? 4 : 12;
  constexpr int K = KT * 32;
  const int t = threadIdx.x;
  const int lane = t & 63;
  const int w = t >> 6;
  const int wm = w >> 1, wn = w & 1;
  const int row_base = blockIdx.x * 64 + wm * 32;
  const int l15 = lane & 15, l16 = lane >> 4;

  __shared__ float lds1[64][2];
  __shared__ float lds2[64][2];
  __shared__ float lds3[64][2];

  f32x4 acc[2][4];
#pragma unroll
  for (int i = 0; i < 2; ++i)
#pragma unroll
    for (int j = 0; j < 4; ++j) acc[i][j] = (f32x4){0.f, 0.f, 0.f, 0.f};

#pragma unroll
  for (int kk = 0; kk < KT; ++kk) {
    short8 a[2], b[4];
#pragma unroll
    for (int i = 0; i < 2; ++i) {
      int row = row_base + i * 16 + l15;
      if (row >= M) row = M - 1;
      if (MODE == 0) {
        const float* xr = Axf + (size_t)row * 128 + kk * 32 + l16 * 8;
        float4 f0 = *(const float4*)xr;
        float4 f1 = *(const float4*)(xr + 4);
        a[i][0] = (short)f2bf(f0.x); a[i][1] = (short)f2bf(f0.y);
        a[i][2] = (short)f2bf(f0.z); a[i][3] = (short)f2bf(f0.w);
        a[i][4] = (short)f2bf(f1.x); a[i][5] = (short)f2bf(f1.y);
        a[i][6] = (short)f2bf(f1.z); a[i][7] = (short)f2bf(f1.w);
      } else {
        if (kk < 4) {
          a[i] = *(const short8*)(A0 + (size_t)row * 128 + kk * 32 + l16 * 8);
        } else {
          a[i] = *(const short8*)(A1 + (size_t)row * 256 + (kk - 4) * 32 + l16 * 8);
        }
      }
    }
#pragma unroll
    for (int j = 0; j < 4; ++j) {
      int col = wn * 64 + j * 16 + l15;
      b[j] = *(const short8*)(W + (size_t)col * K + kk * 32 + l16 * 8);
    }
#pragma unroll
    for (int i = 0; i < 2; ++i)
#pragma unroll
      for (int j = 0; j < 4; ++j)
        acc[i][j] = __builtin_amdgcn_mfma_f32_16x16x32_bf16(a[i], b[j], acc[i][j], 0, 0, 0);
  }

  if (MODE == 0) {
    // relu epilogue + optional score
#pragma unroll
    for (int i = 0; i < 2; ++i)
#pragma unroll
      for (int r = 0; r < 4; ++r) {
        int row = row_base + i * 16 + l16 * 4 + r;
        bool valid = row < M;
        float psc = 0.f;
#pragma unroll
        for (int j = 0; j < 4; ++j) {
          int colw = wn * 64 + j * 16 + l15;
          float v = acc[i][j][r] + bias[colw];
          v = fmaxf(v, 0.f);
          if (valid) {
            h[(size_t)row * 128 + colw] = v;
            hb[(size_t)row * 128 + colw] = f2bf(v);
          }
          if (SCORE) psc += v * Wsc[colw];
        }
        if (SCORE) {
#pragma unroll
          for (int mm = 1; mm <= 8; mm <<= 1) psc += __shfl_xor(psc, mm, 64);
          if (l15 == 0) lds3[wm * 32 + i * 16 + l16 * 4 + r][wn] = psc;
        }
      }
    if (SCORE) {
      __syncthreads();
      if (wn == 0 && l15 == 0) {
#pragma unroll
        for (int i = 0; i < 2; ++i)
#pragma unroll
          for (int r = 0; r < 4; ++r) {
            int rl = wm * 32 + i * 16 + l16 * 4 + r;
            int row = blockIdx.x * 64 + rl;
            if (row < M) scores[row] = lds3[rl][0] + lds3[rl][1] + bsc[0];
          }
      }
    }
  } else {
    // bias + LN stats (pass 1)
#pragma unroll
    for (int i = 0; i < 2; ++i)
#pragma unroll
      for (int r = 0; r < 4; ++r) {
        float p1 = 0.f, p2 = 0.f;
#pragma unroll
        for (int j = 0; j < 4; ++j) {
          int colw = wn * 64 + j * 16 + l15;
          float v = acc[i][j][r] + bias[colw];
          acc[i][j][r] = v;
          p1 += v;
          p2 += v * v;
        }
#pragma unroll
        for (int mm = 1; mm <= 8; mm <<= 1) {
          p1 += __shfl_xor(p1, mm, 64);
          p2 += __shfl_xor(p2, mm, 64);
        }
        if (l15 == 0) {
          int rl = wm * 32 + i * 16 + l16 * 4 + r;
          lds1[rl][wn] = p1;
          lds2[rl][wn] = p2;
        }
      }
    __syncthreads();
    // pass 2: normalize + relu + residual + store (+ score partial)
#pragma unroll
    for (int i = 0; i < 2; ++i)
#pragma unroll
      for (int r = 0; r < 4; ++r) {
        int rl = wm * 32 + i * 16 + l16 * 4 + r;
        int row = blockIdx.x * 64 + rl;
        bool valid = row < M;
        float s1 = lds1[rl][0] + lds1[rl][1];
        float s2 = lds2[rl][0] + lds2[rl][1];
        float mu = s1 * (1.f / 128.f);
        float var = s2 * (1.f / 128.f) - mu * mu;
        float rs = rsqrtf(var + EPS);
        float psc = 0.f;
#pragma unroll
        for (int j = 0; j < 4; ++j) {
          int colw = wn * 64 + j * 16 + l15;
          float v = acc[i][j][r];
          float o = (v - mu) * rs * gamma[colw] + beta[colw];
          o = fmaxf(o, 0.f);
          float res = o;
          if (valid) {
            res = o + h[(size_t)row * 128 + colw];
            h[(size_t)row * 128 + colw] = res;
            hb[(size_t)row * 128 + colw] = f2bf(res);
          }
          if (SCORE) psc += res * Wsc[colw];
        }
        if (SCORE) {
#pragma unroll
          for (int mm = 1; mm <= 8; mm <<= 1) psc += __shfl_xor(psc, mm, 64);
          if (l15 == 0) lds3[rl][wn] = psc;
        }
      }
    if (SCORE) {
      __syncthreads();
      if (wn == 0 && l15 == 0) {
#pragma unroll
        for (int i = 0; i < 2; ++i)
#pragma unroll
          for (int r = 0; r < 4; ++r) {
            int rl = wm * 32 + i * 16 + l16 * 4 + r;
            int row = blockIdx.x * 64 + rl;
            if (row < M) scores[row] = lds3[rl][0] + lds3[rl][1] + bsc[0];
          }
      }
    }
  }
}

// ---------------------------------------------------------------------------
// Weight precompute: Wbig[l][:, p*128:(p+1)*128] = Wcomb[l][:,p-part] @ Wp[l]
// ---------------------------------------------------------------------------
__global__ __launch_bounds__(256) void wpre_kernel(
    const float* __restrict__ Wcomb, const float* __restrict__ Wself,
    const float* __restrict__ Wfwd, const float* __restrict__ Wbwd,
    ushort* __restrict__ Wbig) {
  const int l = blockIdx.x / 3, p = blockIdx.x % 3;
  const float* Wc = Wcomb + (size_t)l * 128 * 384;
  const float* Wp = (p == 0 ? Wself : (p == 1 ? Wfwd : Wbwd)) + (size_t)l * 128 * 128;
  __shared__ float Bs[128][132];
  const int t = threadIdx.x;
  for (int i = t; i < 16384; i += 256) Bs[i >> 7][i & 127] = Wp[i];
  __syncthreads();
  const int r = t >> 1;
  const int c0 = (t & 1) * 64;
  float acc[64];
#pragma unroll
  for (int c = 0; c < 64; ++c) acc[c] = 0.f;
  for (int k = 0; k < 128; ++k) {
    float a = Wc[(size_t)r * 384 + p * 128 + k];
#pragma unroll
    for (int c4 = 0; c4 < 16; ++c4) {
      float4 b4 = *(const float4*)&Bs[k][c0 + c4 * 4];
      acc[c4 * 4 + 0] = fmaf(a, b4.x, acc[c4 * 4 + 0]);
      acc[c4 * 4 + 1] = fmaf(a, b4.y, acc[c4 * 4 + 1]);
      acc[c4 * 4 + 2] = fmaf(a, b4.z, acc[c4 * 4 + 2]);
      acc[c4 * 4 + 3] = fmaf(a, b4.w, acc[c4 * 4 + 3]);
    }
  }
  ushort* o = Wbig + (size_t)l * 128 * 384 + (size_t)r * 384 + p * 128 + c0;
#pragma unroll
  for (int c = 0; c < 64; ++c) o[c] = f2bf(acc[c]);
}

// bias_c[l][c] = bcomb[l][c] + sum_k Wcomb[l][c][k] * bself[l][k]
__global__ void bpre_kernel(const float* __restrict__ Wcomb, const float* __restrict__ bself,
                            const float* __restrict__ bcomb, float* __restrict__ biasc, int L) {
  int idx = blockIdx.x * 128 + threadIdx.x;
  if (idx >= L * 128) return;
  int l = idx >> 7;
  const float* Wc = Wcomb + (size_t)l * 128 * 384 + (size_t)(idx & 127) * 384;
  const float* bs = bself + (size_t)l * 128;
  float acc = bcomb[idx];
  for (int k = 0; k < 128; ++k) acc = fmaf(Wc[k], bs[k], acc);
  biasc[idx] = acc;
}

// fp32 -> bf16 (n4 float4 groups)
__global__ void f2b_kernel(const float* __restrict__ in, ushort* __restrict__ out, int n4) {
  int i = blockIdx.x * 256 + threadIdx.x;
  if (i < n4) {
    float4 v = ((const float4*)in)[i];
    ushort4 o;
    o.x = f2bf(v.x); o.y = f2bf(v.y); o.z = f2bf(v.z); o.w = f2bf(v.w);
    ((ushort4*)out)[i] = o;
  }
}

// ---------------------------------------------------------------------------
// CSR build: histogram -> scan -> scatter (counting sort by dst)
// ---------------------------------------------------------------------------
__global__ void hist_kernel(const int* __restrict__ dst, int* __restrict__ counts, int E) {
  int e = blockIdx.x * 256 + threadIdx.x;
  if (e < E) atomicAdd(&counts[dst[e]], 1);
}

__global__ __launch_bounds__(256) void scan1_kernel(
    const int* __restrict__ c, int* __restrict__ ex, int* __restrict__ partials, int n) {
  __shared__ int sd[256];
  int t = threadIdx.x, b = blockIdx.x;
  int base = b * 1024 + t * 4;
  int v0 = (base + 0 < n) ? c[base + 0] : 0;
  int v1 = (base + 1 < n) ? c[base + 1] : 0;
  int v2 = (base + 2 < n) ? c[base + 2] : 0;
  int v3 = (base + 3 < n) ? c[base + 3] : 0;
  int tot = v0 + v1 + v2 + v3;
  sd[t] = tot;
  __syncthreads();
  for (int off = 1; off < 256; off <<= 1) {
    int x = (t >= off) ? sd[t - off] : 0;
    __syncthreads();
    sd[t] += x;
    __syncthreads();
  }
  int p = sd[t] - tot;
  if (base + 0 < n) ex[base + 0] = p;
  if (base + 1 < n) ex[base + 1] = p + v0;
  if (base + 2 < n) ex[base + 2] = p + v0 + v1;
  if (base + 3 < n) ex[base + 3] = p + v0 + v1 + v2;
  if (t == 255) partials[b] = sd[255];
}

__global__ __launch_bounds__(256) void scan2_kernel(int* __restrict__ partials, int nb) {
  __shared__ int sd[256];
  int t = threadIdx.x;
  int v = (t < nb) ? partials[t] : 0;
  sd[t] = v;
  __syncthreads();
  for (int off = 1; off < 256; off <<= 1) {
    int x = (t >= off) ? sd[t - off] : 0;
    __syncthreads();
    sd[t] += x;
    __syncthreads();
  }
  if (t < nb) partials[t] = sd[t] - v;
}

__global__ void scan3_kernel(const int* __restrict__ ex, const int* __restrict__ partials,
                             int* __restrict__ indptr, int n, int E) {
  int i = blockIdx.x * 256 + threadIdx.x;
  if (i < n) indptr[i] = ex[i] + partials[i >> 10];
  if (i == 0) indptr[n] = E;
}

__global__ void scatter_kernel(const int* __restrict__ ei, int* __restrict__ cursor,
                               int* __restrict__ ssrc, int E) {
  int e = blockIdx.x * 256 + threadIdx.x;
  if (e >= E) return;
  int s = ei[e];
  int d = ei[E + e];
  int pos = atomicAdd(&cursor[d], 1);
  ssrc[pos] = s;
}

// ---------------------------------------------------------------------------
// Edge aggregation: 1 wave/node. Lane-parallel prefetch of up to 64 edges'
// (src, alpha); inner loop broadcasts (s,alpha) and streams independent
// 256B row loads. u = sum al*h[s]; v = sum h[s] - u. uv[N][256] bf16.
// ---------------------------------------------------------------------------
__global__ __launch_bounds__(256) void aggr_kernel(
    const int* __restrict__ indptr, const int* __restrict__ ssrc,
    const float* __restrict__ scores, const ushort* __restrict__ hb,
    ushort* __restrict__ uv, int Nn) {
  int node = blockIdx.x * 4 + (threadIdx.x >> 6);
  if (node >= Nn) return;
  int lane = threadIdx.x & 63;
  int beg = indptr[node], end = indptr[node + 1];
  float si = scores[node];
  float u0 = 0.f, u1 = 0.f, t0 = 0.f, t1 = 0.f;
  for (int ebase = beg; ebase < end; ebase += 64) {
    int cnt = min(64, end - ebase);
    int sv = 0;
    float al = 0.f;
    if (lane < cnt) {
      sv = ssrc[ebase + lane];
      al = 1.f / (1.f + __expf(si - scores[sv]));  // sigmoid(scores[s]-si)
    }
    for (int e = 0; e < cnt; ++e) {
      int s_e = __shfl(sv, e, 64);
      float a_e = __shfl(al, e, 64);
      unsigned vv = *(const unsigned*)(hb + (size_t)s_e * 128 + lane * 2);
      float f0 = bflo(vv), f1 = bfhi(vv);
      u0 = fmaf(a_e, f0, u0);
      u1 = fmaf(a_e, f1, u1);
      t0 += f0;
      t1 += f1;
    }
  }
  unsigned pu = (unsigned)f2bf(u0) | ((unsigned)f2bf(u1) << 16);
  unsigned pv = (unsigned)f2bf(t0 - u0) | ((unsigned)f2bf(t1 - u1) << 16);
  *(unsigned*)(uv + (size_t)node * 256 + lane * 2) = pu;
  *(unsigned*)(uv + (size_t)node * 256 + 128 + lane * 2) = pv;
}

// ---------------------------------------------------------------------------
// Global mean pool (batch sorted): deterministic two-stage, no atomics.
// Stage: block (g, s) sums slice s of group g's rows -> partial[g][s][128].
// Finalize: out[g][d] = sum_s partial / count(g).
// ---------------------------------------------------------------------------
__global__ __launch_bounds__(128) void pool_stage_kernel(
    const float* __restrict__ h, const int* __restrict__ batch,
    float* __restrict__ partial, int M) {
  int g = blockIdx.x, s = blockIdx.y, d = threadIdx.x;
  int lo = 0, hi = M;
  while (lo < hi) { int mid = (lo + hi) >> 1; if (batch[mid] < g) lo = mid + 1; else hi = mid; }
  int b0 = lo;
  hi = M;
  while (lo < hi) { int mid = (lo + hi) >> 1; if (batch[mid] <= g) lo = mid + 1; else hi = mid; }
  int b1 = lo;
  int len = b1 - b0;
  int chunk = (len + PS - 1) / PS;
  int r0 = b0 + s * chunk;
  int r1 = min(b1, r0 + chunk);
  float acc = 0.f;
  for (int i = r0; i < r1; ++i) acc += h[(size_t)i * 128 + d];
  partial[((size_t)g * PS + s) * 128 + d] = acc;
}

__global__ void pool_final_kernel(const float* __restrict__ partial,
                                  const int* __restrict__ batch,
                                  float* __restrict__ out, int M, int G) {
  int idx = blockIdx.x * 256 + threadIdx.x;
  if (idx >= G * 128) return;
  int g = idx >> 7, d = idx & 127;
  float acc = 0.f;
#pragma unroll
  for (int s = 0; s < PS; ++s) acc += partial[((size_t)g * PS + s) * 128 + d];
  int lo = 0, hi = M;
  while (lo < hi) { int mid = (lo + hi) >> 1; if (batch[mid] < g) lo = mid + 1; else hi = mid; }
  int b0 = lo;
  hi = M;
  while (lo < hi) { int mid = (lo + hi) >> 1; if (batch[mid] <= g) lo = mid + 1; else hi = mid; }
  int c = lo - b0;
  out[idx] = acc / (float)(c > 0 ? c : 1);
}

// ---------------------------------------------------------------------------
extern "C" void kernel_launch(void* const* d_in, const int* in_sizes, int n_in,
                              void* d_out, int out_size, void* d_ws, size_t ws_size,
                              hipStream_t stream) {
  const float* x      = (const float*)d_in[0];
  const int*   ei     = (const int*)d_in[1];
  const int*   batch  = (const int*)d_in[2];
  const float* Wemb   = (const float*)d_in[3];
  const float* bemb   = (const float*)d_in[4];
  const float* Wscore = (const float*)d_in[5];
  const float* bscore = (const float*)d_in[6];
  const float* Wfwd   = (const float*)d_in[7];
  const float* Wbwd   = (const float*)d_in[8];
  const float* Wself  = (const float*)d_in[9];
  const float* bself  = (const float*)d_in[10];
  const float* Wcomb  = (const float*)d_in[11];
  const float* bcomb  = (const float*)d_in[12];
  const float* gamma  = (const float*)d_in[13];
  const float* beta   = (const float*)d_in[14];

  const int N = in_sizes[0] / 128;
  const int E = in_sizes[1] / 2;
  const int L = in_sizes[5] / 128;
  const int G = out_size / 128;
  float* out = (float*)d_out;

  char* p = (char*)d_ws;
  auto alloc = [&](size_t bytes) -> char* {
    char* r = p;
    p += (bytes + 255) & ~(size_t)255;
    return r;
  };
  float*  h      = (float*)alloc((size_t)N * 128 * 4);
  ushort* hb16   = (ushort*)alloc((size_t)N * 128 * 2);
  ushort* uv     = (ushort*)alloc((size_t)N * 256 * 2);   // [u | v] bf16
  float*  scores = (float*)alloc((size_t)N * 4);
  ushort* Wemb_b = (ushort*)alloc(16384 * 2);
  ushort* Wbig   = (ushort*)alloc((size_t)L * 128 * 384 * 2);
  float*  biasc  = (float*)alloc((size_t)L * 128 * 4);
  int* counts    = (int*)alloc((size_t)N * 4);
  int* ex        = (int*)alloc((size_t)N * 4);
  int* partials  = (int*)alloc(1024);
  int* indptr    = (int*)alloc((size_t)(N + 1) * 4);
  int* cursor    = (int*)alloc((size_t)N * 4);
  int* ssrc      = (int*)alloc((size_t)E * 4);
  float* pool_p  = (float*)alloc((size_t)G * PS * 128 * 4);

  const int gb = (N + 63) / 64;

  // 0. precompute: weight conversions + combined weights
  f2b_kernel<<<16, 256, 0, stream>>>(Wemb, Wemb_b, 4096);
  wpre_kernel<<<3 * L, 256, 0, stream>>>(Wcomb, Wself, Wfwd, Wbwd, Wbig);
  bpre_kernel<<<L, 128, 0, stream>>>(Wcomb, bself, bcomb, biasc, L);

  // 1. CSR build (edges constant within a call)
  hipMemsetAsync(counts, 0, (size_t)N * 4, stream);
  hist_kernel<<<(E + 255) / 256, 256, 0, stream>>>(ei + E, counts, E);
  int nb = (N + 1023) / 1024;
  scan1_kernel<<<nb, 256, 0, stream>>>(counts, ex, partials, N);
  scan2_kernel<<<1, 256, 0, stream>>>(partials, nb);
  scan3_kernel<<<(N + 255) / 256, 256, 0, stream>>>(ex, partials, indptr, N, E);
  hipMemcpyAsync(cursor, indptr, (size_t)N * 4, hipMemcpyDeviceToDevice, stream);
  scatter_kernel<<<(E + 255) / 256, 256, 0, stream>>>(ei, cursor, ssrc, E);

  // 2. embedding: h = relu(x @ Wemb^T + bemb), fused layer-0 scores
  fused_gemm<0, true><<<gb, 256, 0, stream>>>(
      x, nullptr, nullptr, Wemb_b, bemb, nullptr, nullptr,
      Wscore, bscore, h, hb16, scores, N);

  // 3. layers: aggr -> fused GEMM+LN+residual(+next scores)
  for (int l = 0; l < L; ++l) {
    aggr_kernel<<<(N + 3) / 4, 256, 0, stream>>>(indptr, ssrc, scores, hb16, uv, N);
    if (l < L - 1) {
      fused_gemm<1, true><<<gb, 256, 0, stream>>>(
          nullptr, hb16, uv, Wbig + (size_t)l * 128 * 384, biasc + (size_t)l * 128,
          gamma + (size_t)l * 128, beta + (size_t)l * 128,
          Wscore + (size_t)(l + 1) * 128, bscore + (l + 1), h, hb16, scores, N);
    } else {
      fused_gemm<1, false><<<gb, 256, 0, stream>>>(
          nullptr, hb16, uv, Wbig + (size_t)l * 128 * 384, biasc + (size_t)l * 128,
          gamma + (size_t)l * 128, beta + (size_t)l * 128,
          nullptr, nullptr, h, hb16, scores, N);
    }
  }

  // 4. global mean pool (two-stage, no atomics)
  pool_stage_kernel<<<dim3(G, PS), 128, 0, stream>>>(h, batch, pool_p, N);
  pool_final_kernel<<<(G * 128 + 255) / 256, 256, 0, stream>>>(pool_p, batch, out, N, G);
}

// Round 7
// 556.422 us; speedup vs baseline: 1.0231x; 1.0231x over previous
//
#include <hip/hip_runtime.h>
#include <math.h>

#define EPS 1e-5f
#define PS 8  // pool slices per group

typedef __attribute__((ext_vector_type(8))) short short8;
typedef __attribute__((ext_vector_type(4))) float f32x4;

__device__ __forceinline__ float bflo(unsigned u) {
  union { unsigned i; float f; } c; c.i = u << 16; return c.f;
}
__device__ __forceinline__ float bfhi(unsigned u) {
  union { unsigned i; float f; } c; c.i = u & 0xFFFF0000u; return c.f;
}
__device__ __forceinline__ unsigned short f2bf(float f) {
  union { float f; unsigned i; } c; c.f = f;
  unsigned r = c.i + 0x7FFF + ((c.i >> 16) & 1);
  return (unsigned short)(r >> 16);
}

// ---------------------------------------------------------------------------
// Embed GEMM (K=128): h = relu(x_f32 @ W^T + bias); h fp32 + hb bf16 (+score).
// BM=64/block, 4 waves 2x2, wave tile 32x64. Single load burst then MFMA.
// ---------------------------------------------------------------------------
template <bool SCORE>
__global__ __launch_bounds__(256, 2) void embed_gemm(
    const float* __restrict__ Axf, const ushort* __restrict__ W,
    const float* __restrict__ bias, const float* __restrict__ Wsc,
    const float* __restrict__ bsc, float* __restrict__ h,
    ushort* __restrict__ hb, float* __restrict__ scores, int M) {
  const int t = threadIdx.x;
  const int lane = t & 63;
  const int w = t >> 6;
  const int wm = w >> 1, wn = w & 1;
  const int row_base = blockIdx.x * 64 + wm * 32;
  const int l15 = lane & 15, l16 = lane >> 4;

  __shared__ float lds3[64][2];

  int r0 = row_base + l15;      if (r0 >= M) r0 = M - 1;
  int r1 = row_base + 16 + l15; if (r1 >= M) r1 = M - 1;
  const float* xp[2] = { Axf + (size_t)r0 * 128 + l16 * 8,
                         Axf + (size_t)r1 * 128 + l16 * 8 };
  const ushort* wp[4];
#pragma unroll
  for (int j = 0; j < 4; ++j)
    wp[j] = W + (size_t)(wn * 64 + j * 16 + l15) * 128 + l16 * 8;

  // load everything (16 x-pairs fp32 + 16 W frags), convert, then MFMA
  short8 Ab[2][4], Wb[4][4];
#pragma unroll
  for (int kk = 0; kk < 4; ++kk) {
#pragma unroll
    for (int i = 0; i < 2; ++i) {
      const float* xr = xp[i] + kk * 32;
      float4 f0 = *(const float4*)xr;
      float4 f1 = *(const float4*)(xr + 4);
      short8 v;
      v[0] = (short)f2bf(f0.x); v[1] = (short)f2bf(f0.y);
      v[2] = (short)f2bf(f0.z); v[3] = (short)f2bf(f0.w);
      v[4] = (short)f2bf(f1.x); v[5] = (short)f2bf(f1.y);
      v[6] = (short)f2bf(f1.z); v[7] = (short)f2bf(f1.w);
      Ab[i][kk] = v;
    }
#pragma unroll
    for (int j = 0; j < 4; ++j) Wb[j][kk] = *(const short8*)(wp[j] + kk * 32);
  }

  f32x4 acc[2][4];
#pragma unroll
  for (int i = 0; i < 2; ++i)
#pragma unroll
    for (int j = 0; j < 4; ++j) acc[i][j] = (f32x4){0.f, 0.f, 0.f, 0.f};
#pragma unroll
  for (int kk = 0; kk < 4; ++kk)
#pragma unroll
    for (int i = 0; i < 2; ++i)
#pragma unroll
      for (int j = 0; j < 4; ++j)
        acc[i][j] = __builtin_amdgcn_mfma_f32_16x16x32_bf16(Ab[i][kk], Wb[j][kk],
                                                            acc[i][j], 0, 0, 0);

  // epilogue: relu + stores + optional score
#pragma unroll
  for (int i = 0; i < 2; ++i)
#pragma unroll
    for (int r = 0; r < 4; ++r) {
      int row = row_base + i * 16 + l16 * 4 + r;
      bool valid = row < M;
      float psc = 0.f;
#pragma unroll
      for (int j = 0; j < 4; ++j) {
        int colw = wn * 64 + j * 16 + l15;
        float v = acc[i][j][r] + bias[colw];
        v = fmaxf(v, 0.f);
        if (valid) {
          h[(size_t)row * 128 + colw] = v;
          hb[(size_t)row * 128 + colw] = f2bf(v);
        }
        if (SCORE) psc += v * Wsc[colw];
      }
      if (SCORE) {
#pragma unroll
        for (int mm = 1; mm <= 8; mm <<= 1) psc += __shfl_xor(psc, mm, 64);
        if (l15 == 0) lds3[wm * 32 + i * 16 + l16 * 4 + r][wn] = psc;
      }
    }
  if (SCORE) {
    __syncthreads();
    if (wn == 0 && l15 == 0) {
#pragma unroll
      for (int i = 0; i < 2; ++i)
#pragma unroll
        for (int r = 0; r < 4; ++r) {
          int rl = wm * 32 + i * 16 + l16 * 4 + r;
          int row = blockIdx.x * 64 + rl;
          if (row < M) scores[row] = lds3[rl][0] + lds3[rl][1] + bsc[0];
        }
    }
  }
}

// ---------------------------------------------------------------------------
// Layer GEMM (K=384): z = [hb | uv] @ Wbig^T + biasc; LayerNorm; relu;
// += residual h; writes h fp32 + hb bf16 (+ next-layer score).
// BM=64/block, 4 waves 2x2, wave tile 32x64.
// K chunked 4x(3 k-steps); register double-buffer: chunk c+1 loads issued
// before chunk c MFMAs -> 18 loads in flight over 24 MFMAs (latency hiding).
// ---------------------------------------------------------------------------
template <bool SCORE>
__global__ __launch_bounds__(256, 2) void layer_gemm(
    const ushort* __restrict__ A0,    // hb [M][128]
    const ushort* __restrict__ A1,    // uv [M][256]
    const ushort* __restrict__ W,     // Wbig [128][384]
    const float* __restrict__ bias,
    const float* __restrict__ gamma, const float* __restrict__ beta,
    const float* __restrict__ Wsc, const float* __restrict__ bsc,
    float* __restrict__ h, ushort* __restrict__ hb,
    float* __restrict__ scores, int M) {
  const int t = threadIdx.x;
  const int lane = t & 63;
  const int w = t >> 6;
  const int wm = w >> 1, wn = w & 1;
  const int row_base = blockIdx.x * 64 + wm * 32;
  const int l15 = lane & 15, l16 = lane >> 4;

  __shared__ float lds1[64][2];
  __shared__ float lds2[64][2];
  __shared__ float lds3[64][2];

  int r0 = row_base + l15;      if (r0 >= M) r0 = M - 1;
  int r1 = row_base + 16 + l15; if (r1 >= M) r1 = M - 1;
  const ushort* a0p[2] = { A0 + (size_t)r0 * 128 + l16 * 8,
                           A0 + (size_t)r1 * 128 + l16 * 8 };
  const ushort* a1p[2] = { A1 + (size_t)r0 * 256 + l16 * 8,
                           A1 + (size_t)r1 * 256 + l16 * 8 };
  const ushort* wp[4];
#pragma unroll
  for (int j = 0; j < 4; ++j)
    wp[j] = W + (size_t)(wn * 64 + j * 16 + l15) * 384 + l16 * 8;

  short8 Ab[2][2][3];  // [buf][i][q]
  short8 Wb[2][4][3];  // [buf][j][q]
  f32x4 acc[2][4];
#pragma unroll
  for (int i = 0; i < 2; ++i)
#pragma unroll
    for (int j = 0; j < 4; ++j) acc[i][j] = (f32x4){0.f, 0.f, 0.f, 0.f};

  // chunk c covers kk = 3c + q, q in [0,3)
#pragma unroll
  for (int c = 0; c < 4; ++c) {
    const int cur = c & 1, nxt = cur ^ 1;
    if (c == 0) {
#pragma unroll
      for (int q = 0; q < 3; ++q) {
        const int kk = q;  // all < 4 -> A0
#pragma unroll
        for (int i = 0; i < 2; ++i)
          Ab[0][i][q] = *(const short8*)(a0p[i] + kk * 32);
#pragma unroll
        for (int j = 0; j < 4; ++j)
          Wb[0][j][q] = *(const short8*)(wp[j] + kk * 32);
      }
    }
    if (c < 3) {
      // prefetch chunk c+1 into nxt (issued before this chunk's MFMAs)
#pragma unroll
      for (int q = 0; q < 3; ++q) {
        const int kk = (c + 1) * 3 + q;
#pragma unroll
        for (int i = 0; i < 2; ++i) {
          if (kk < 4)
            Ab[nxt][i][q] = *(const short8*)(a0p[i] + kk * 32);
          else
            Ab[nxt][i][q] = *(const short8*)(a1p[i] + (kk - 4) * 32);
        }
#pragma unroll
        for (int j = 0; j < 4; ++j)
          Wb[nxt][j][q] = *(const short8*)(wp[j] + kk * 32);
      }
    }
#pragma unroll
    for (int q = 0; q < 3; ++q)
#pragma unroll
      for (int i = 0; i < 2; ++i)
#pragma unroll
        for (int j = 0; j < 4; ++j)
          acc[i][j] = __builtin_amdgcn_mfma_f32_16x16x32_bf16(
              Ab[cur][i][q], Wb[cur][j][q], acc[i][j], 0, 0, 0);
  }

  // bias + LN stats (pass 1)
#pragma unroll
  for (int i = 0; i < 2; ++i)
#pragma unroll
    for (int r = 0; r < 4; ++r) {
      float p1 = 0.f, p2 = 0.f;
#pragma unroll
      for (int j = 0; j < 4; ++j) {
        int colw = wn * 64 + j * 16 + l15;
        float v = acc[i][j][r] + bias[colw];
        acc[i][j][r] = v;
        p1 += v;
        p2 += v * v;
      }
#pragma unroll
      for (int mm = 1; mm <= 8; mm <<= 1) {
        p1 += __shfl_xor(p1, mm, 64);
        p2 += __shfl_xor(p2, mm, 64);
      }
      if (l15 == 0) {
        int rl = wm * 32 + i * 16 + l16 * 4 + r;
        lds1[rl][wn] = p1;
        lds2[rl][wn] = p2;
      }
    }
  __syncthreads();
  // pass 2: normalize + relu + residual + store (+ score partial)
#pragma unroll
  for (int i = 0; i < 2; ++i)
#pragma unroll
    for (int r = 0; r < 4; ++r) {
      int rl = wm * 32 + i * 16 + l16 * 4 + r;
      int row = blockIdx.x * 64 + rl;
      bool valid = row < M;
      float s1 = lds1[rl][0] + lds1[rl][1];
      float s2 = lds2[rl][0] + lds2[rl][1];
      float mu = s1 * (1.f / 128.f);
      float var = s2 * (1.f / 128.f) - mu * mu;
      float rs = rsqrtf(var + EPS);
      float psc = 0.f;
#pragma unroll
      for (int j = 0; j < 4; ++j) {
        int colw = wn * 64 + j * 16 + l15;
        float v = acc[i][j][r];
        float o = (v - mu) * rs * gamma[colw] + beta[colw];
        o = fmaxf(o, 0.f);
        float res = o;
        if (valid) {
          res = o + h[(size_t)row * 128 + colw];
          h[(size_t)row * 128 + colw] = res;
          hb[(size_t)row * 128 + colw] = f2bf(res);
        }
        if (SCORE) psc += res * Wsc[colw];
      }
      if (SCORE) {
#pragma unroll
        for (int mm = 1; mm <= 8; mm <<= 1) psc += __shfl_xor(psc, mm, 64);
        if (l15 == 0) lds3[rl][wn] = psc;
      }
    }
  if (SCORE) {
    __syncthreads();
    if (wn == 0 && l15 == 0) {
#pragma unroll
      for (int i = 0; i < 2; ++i)
#pragma unroll
        for (int r = 0; r < 4; ++r) {
          int rl = wm * 32 + i * 16 + l16 * 4 + r;
          int row = blockIdx.x * 64 + rl;
          if (row < M) scores[row] = lds3[rl][0] + lds3[rl][1] + bsc[0];
        }
    }
  }
}

// ---------------------------------------------------------------------------
// Weight precompute: Wbig[l][:, p*128:(p+1)*128] = Wcomb[l][:,p-part] @ Wp[l]
// ---------------------------------------------------------------------------
__global__ __launch_bounds__(256) void wpre_kernel(
    const float* __restrict__ Wcomb, const float* __restrict__ Wself,
    const float* __restrict__ Wfwd, const float* __restrict__ Wbwd,
    ushort* __restrict__ Wbig) {
  const int l = blockIdx.x / 3, p = blockIdx.x % 3;
  const float* Wc = Wcomb + (size_t)l * 128 * 384;
  const float* Wp = (p == 0 ? Wself : (p == 1 ? Wfwd : Wbwd)) + (size_t)l * 128 * 128;
  __shared__ float Bs[128][132];
  const int t = threadIdx.x;
  for (int i = t; i < 16384; i += 256) Bs[i >> 7][i & 127] = Wp[i];
  __syncthreads();
  const int r = t >> 1;
  const int c0 = (t & 1) * 64;
  float acc[64];
#pragma unroll
  for (int c = 0; c < 64; ++c) acc[c] = 0.f;
  for (int k = 0; k < 128; ++k) {
    float a = Wc[(size_t)r * 384 + p * 128 + k];
#pragma unroll
    for (int c4 = 0; c4 < 16; ++c4) {
      float4 b4 = *(const float4*)&Bs[k][c0 + c4 * 4];
      acc[c4 * 4 + 0] = fmaf(a, b4.x, acc[c4 * 4 + 0]);
      acc[c4 * 4 + 1] = fmaf(a, b4.y, acc[c4 * 4 + 1]);
      acc[c4 * 4 + 2] = fmaf(a, b4.z, acc[c4 * 4 + 2]);
      acc[c4 * 4 + 3] = fmaf(a, b4.w, acc[c4 * 4 + 3]);
    }
  }
  ushort* o = Wbig + (size_t)l * 128 * 384 + (size_t)r * 384 + p * 128 + c0;
#pragma unroll
  for (int c = 0; c < 64; ++c) o[c] = f2bf(acc[c]);
}

// bias_c[l][c] = bcomb[l][c] + sum_k Wcomb[l][c][k] * bself[l][k]
__global__ void bpre_kernel(const float* __restrict__ Wcomb, const float* __restrict__ bself,
                            const float* __restrict__ bcomb, float* __restrict__ biasc, int L) {
  int idx = blockIdx.x * 128 + threadIdx.x;
  if (idx >= L * 128) return;
  int l = idx >> 7;
  const float* Wc = Wcomb + (size_t)l * 128 * 384 + (size_t)(idx & 127) * 384;
  const float* bs = bself + (size_t)l * 128;
  float acc = bcomb[idx];
  for (int k = 0; k < 128; ++k) acc = fmaf(Wc[k], bs[k], acc);
  biasc[idx] = acc;
}

// fp32 -> bf16 (n4 float4 groups)
__global__ void f2b_kernel(const float* __restrict__ in, ushort* __restrict__ out, int n4) {
  int i = blockIdx.x * 256 + threadIdx.x;
  if (i < n4) {
    float4 v = ((const float4*)in)[i];
    ushort4 o;
    o.x = f2bf(v.x); o.y = f2bf(v.y); o.z = f2bf(v.z); o.w = f2bf(v.w);
    ((ushort4*)out)[i] = o;
  }
}

// ---------------------------------------------------------------------------
// CSR build: histogram -> scan -> scatter (counting sort by dst)
// ---------------------------------------------------------------------------
__global__ void hist_kernel(const int* __restrict__ dst, int* __restrict__ counts, int E) {
  int e = blockIdx.x * 256 + threadIdx.x;
  if (e < E) atomicAdd(&counts[dst[e]], 1);
}

__global__ __launch_bounds__(256) void scan1_kernel(
    const int* __restrict__ c, int* __restrict__ ex, int* __restrict__ partials, int n) {
  __shared__ int sd[256];
  int t = threadIdx.x, b = blockIdx.x;
  int base = b * 1024 + t * 4;
  int v0 = (base + 0 < n) ? c[base + 0] : 0;
  int v1 = (base + 1 < n) ? c[base + 1] : 0;
  int v2 = (base + 2 < n) ? c[base + 2] : 0;
  int v3 = (base + 3 < n) ? c[base + 3] : 0;
  int tot = v0 + v1 + v2 + v3;
  sd[t] = tot;
  __syncthreads();
  for (int off = 1; off < 256; off <<= 1) {
    int x = (t >= off) ? sd[t - off] : 0;
    __syncthreads();
    sd[t] += x;
    __syncthreads();
  }
  int p = sd[t] - tot;
  if (base + 0 < n) ex[base + 0] = p;
  if (base + 1 < n) ex[base + 1] = p + v0;
  if (base + 2 < n) ex[base + 2] = p + v0 + v1;
  if (base + 3 < n) ex[base + 3] = p + v0 + v1 + v2;
  if (t == 255) partials[b] = sd[255];
}

__global__ __launch_bounds__(256) void scan2_kernel(int* __restrict__ partials, int nb) {
  __shared__ int sd[256];
  int t = threadIdx.x;
  int v = (t < nb) ? partials[t] : 0;
  sd[t] = v;
  __syncthreads();
  for (int off = 1; off < 256; off <<= 1) {
    int x = (t >= off) ? sd[t - off] : 0;
    __syncthreads();
    sd[t] += x;
    __syncthreads();
  }
  if (t < nb) partials[t] = sd[t] - v;
}

__global__ void scan3_kernel(const int* __restrict__ ex, const int* __restrict__ partials,
                             int* __restrict__ indptr, int n, int E) {
  int i = blockIdx.x * 256 + threadIdx.x;
  if (i < n) indptr[i] = ex[i] + partials[i >> 10];
  if (i == 0) indptr[n] = E;
}

__global__ void scatter_kernel(const int* __restrict__ ei, int* __restrict__ cursor,
                               int* __restrict__ ssrc, int E) {
  int e = blockIdx.x * 256 + threadIdx.x;
  if (e >= E) return;
  int s = ei[e];
  int d = ei[E + e];
  int pos = atomicAdd(&cursor[d], 1);
  ssrc[pos] = s;
}

// ---------------------------------------------------------------------------
// Edge aggregation: 1 wave/node. Lane-parallel prefetch of up to 64 edges'
// (src, alpha); inner loop broadcasts (s,alpha) and streams independent
// 256B row loads. u = sum al*h[s]; v = sum h[s] - u. uv[N][256] bf16.
// ---------------------------------------------------------------------------
__global__ __launch_bounds__(256) void aggr_kernel(
    const int* __restrict__ indptr, const int* __restrict__ ssrc,
    const float* __restrict__ scores, const ushort* __restrict__ hb,
    ushort* __restrict__ uv, int Nn) {
  int node = blockIdx.x * 4 + (threadIdx.x >> 6);
  if (node >= Nn) return;
  int lane = threadIdx.x & 63;
  int beg = indptr[node], end = indptr[node + 1];
  float si = scores[node];
  float u0 = 0.f, u1 = 0.f, t0 = 0.f, t1 = 0.f;
  for (int ebase = beg; ebase < end; ebase += 64) {
    int cnt = min(64, end - ebase);
    int sv = 0;
    float al = 0.f;
    if (lane < cnt) {
      sv = ssrc[ebase + lane];
      al = 1.f / (1.f + __expf(si - scores[sv]));  // sigmoid(scores[s]-si)
    }
    for (int e = 0; e < cnt; ++e) {
      int s_e = __shfl(sv, e, 64);
      float a_e = __shfl(al, e, 64);
      unsigned vv = *(const unsigned*)(hb + (size_t)s_e * 128 + lane * 2);
      float f0 = bflo(vv), f1 = bfhi(vv);
      u0 = fmaf(a_e, f0, u0);
      u1 = fmaf(a_e, f1, u1);
      t0 += f0;
      t1 += f1;
    }
  }
  unsigned pu = (unsigned)f2bf(u0) | ((unsigned)f2bf(u1) << 16);
  unsigned pv = (unsigned)f2bf(t0 - u0) | ((unsigned)f2bf(t1 - u1) << 16);
  *(unsigned*)(uv + (size_t)node * 256 + lane * 2) = pu;
  *(unsigned*)(uv + (size_t)node * 256 + 128 + lane * 2) = pv;
}

// ---------------------------------------------------------------------------
// Global mean pool (batch sorted): deterministic two-stage, no atomics.
// ---------------------------------------------------------------------------
__global__ __launch_bounds__(128) void pool_stage_kernel(
    const float* __restrict__ h, const int* __restrict__ batch,
    float* __restrict__ partial, int M) {
  int g = blockIdx.x, s = blockIdx.y, d = threadIdx.x;
  int lo = 0, hi = M;
  while (lo < hi) { int mid = (lo + hi) >> 1; if (batch[mid] < g) lo = mid + 1; else hi = mid; }
  int b0 = lo;
  hi = M;
  while (lo < hi) { int mid = (lo + hi) >> 1; if (batch[mid] <= g) lo = mid + 1; else hi = mid; }
  int b1 = lo;
  int len = b1 - b0;
  int chunk = (len + PS - 1) / PS;
  int r0 = b0 + s * chunk;
  int r1 = min(b1, r0 + chunk);
  float acc = 0.f;
  for (int i = r0; i < r1; ++i) acc += h[(size_t)i * 128 + d];
  partial[((size_t)g * PS + s) * 128 + d] = acc;
}

__global__ void pool_final_kernel(const float* __restrict__ partial,
                                  const int* __restrict__ batch,
                                  float* __restrict__ out, int M, int G) {
  int idx = blockIdx.x * 256 + threadIdx.x;
  if (idx >= G * 128) return;
  int g = idx >> 7, d = idx & 127;
  float acc = 0.f;
#pragma unroll
  for (int s = 0; s < PS; ++s) acc += partial[((size_t)g * PS + s) * 128 + d];
  int lo = 0, hi = M;
  while (lo < hi) { int mid = (lo + hi) >> 1; if (batch[mid] < g) lo = mid + 1; else hi = mid; }
  int b0 = lo;
  hi = M;
  while (lo < hi) { int mid = (lo + hi) >> 1; if (batch[mid] <= g) lo = mid + 1; else hi = mid; }
  int c = lo - b0;
  out[idx] = acc / (float)(c > 0 ? c : 1);
}

// ---------------------------------------------------------------------------
extern "C" void kernel_launch(void* const* d_in, const int* in_sizes, int n_in,
                              void* d_out, int out_size, void* d_ws, size_t ws_size,
                              hipStream_t stream) {
  const float* x      = (const float*)d_in[0];
  const int*   ei     = (const int*)d_in[1];
  const int*   batch  = (const int*)d_in[2];
  const float* Wemb   = (const float*)d_in[3];
  const float* bemb   = (const float*)d_in[4];
  const float* Wscore = (const float*)d_in[5];
  const float* bscore = (const float*)d_in[6];
  const float* Wfwd   = (const float*)d_in[7];
  const float* Wbwd   = (const float*)d_in[8];
  const float* Wself  = (const float*)d_in[9];
  const float* bself  = (const float*)d_in[10];
  const float* Wcomb  = (const float*)d_in[11];
  const float* bcomb  = (const float*)d_in[12];
  const float* gamma  = (const float*)d_in[13];
  const float* beta   = (const float*)d_in[14];

  const int N = in_sizes[0] / 128;
  const int E = in_sizes[1] / 2;
  const int L = in_sizes[5] / 128;
  const int G = out_size / 128;
  float* out = (float*)d_out;

  char* p = (char*)d_ws;
  auto alloc = [&](size_t bytes) -> char* {
    char* r = p;
    p += (bytes + 255) & ~(size_t)255;
    return r;
  };
  float*  h      = (float*)alloc((size_t)N * 128 * 4);
  ushort* hb16   = (ushort*)alloc((size_t)N * 128 * 2);
  ushort* uv     = (ushort*)alloc((size_t)N * 256 * 2);   // [u | v] bf16
  float*  scores = (float*)alloc((size_t)N * 4);
  ushort* Wemb_b = (ushort*)alloc(16384 * 2);
  ushort* Wbig   = (ushort*)alloc((size_t)L * 128 * 384 * 2);
  float*  biasc  = (float*)alloc((size_t)L * 128 * 4);
  int* counts    = (int*)alloc((size_t)N * 4);
  int* ex        = (int*)alloc((size_t)N * 4);
  int* partials  = (int*)alloc(1024);
  int* indptr    = (int*)alloc((size_t)(N + 1) * 4);
  int* cursor    = (int*)alloc((size_t)N * 4);
  int* ssrc      = (int*)alloc((size_t)E * 4);
  float* pool_p  = (float*)alloc((size_t)G * PS * 128 * 4);

  const int gb = (N + 63) / 64;

  // 0. precompute: weight conversions + combined weights
  f2b_kernel<<<16, 256, 0, stream>>>(Wemb, Wemb_b, 4096);
  wpre_kernel<<<3 * L, 256, 0, stream>>>(Wcomb, Wself, Wfwd, Wbwd, Wbig);
  bpre_kernel<<<L, 128, 0, stream>>>(Wcomb, bself, bcomb, biasc, L);

  // 1. CSR build (edges constant within a call)
  hipMemsetAsync(counts, 0, (size_t)N * 4, stream);
  hist_kernel<<<(E + 255) / 256, 256, 0, stream>>>(ei + E, counts, E);
  int nb = (N + 1023) / 1024;
  scan1_kernel<<<nb, 256, 0, stream>>>(counts, ex, partials, N);
  scan2_kernel<<<1, 256, 0, stream>>>(partials, nb);
  scan3_kernel<<<(N + 255) / 256, 256, 0, stream>>>(ex, partials, indptr, N, E);
  hipMemcpyAsync(cursor, indptr, (size_t)N * 4, hipMemcpyDeviceToDevice, stream);
  scatter_kernel<<<(E + 255) / 256, 256, 0, stream>>>(ei, cursor, ssrc, E);

  // 2. embedding: h = relu(x @ Wemb^T + bemb), fused layer-0 scores
  embed_gemm<true><<<gb, 256, 0, stream>>>(x, Wemb_b, bemb, Wscore, bscore,
                                           h, hb16, scores, N);

  // 3. layers: aggr -> fused GEMM+LN+residual(+next scores)
  for (int l = 0; l < L; ++l) {
    aggr_kernel<<<(N + 3) / 4, 256, 0, stream>>>(indptr, ssrc, scores, hb16, uv, N);
    if (l < L - 1) {
      layer_gemm<true><<<gb, 256, 0, stream>>>(
          hb16, uv, Wbig + (size_t)l * 128 * 384, biasc + (size_t)l * 128,
          gamma + (size_t)l * 128, beta + (size_t)l * 128,
          Wscore + (size_t)(l + 1) * 128, bscore + (l + 1), h, hb16, scores, N);
    } else {
      layer_gemm<false><<<gb, 256, 0, stream>>>(
          hb16, uv, Wbig + (size_t)l * 128 * 384, biasc + (size_t)l * 128,
          gamma + (size_t)l * 128, beta + (size_t)l * 128,
          nullptr, nullptr, h, hb16, scores, N);
    }
  }

  // 4. global mean pool (two-stage, no atomics)
  pool_stage_kernel<<<dim3(G, PS), 128, 0, stream>>>(h, batch, pool_p, N);
  pool_final_kernel<<<(G * 128 + 255) / 256, 256, 0, stream>>>(pool_p, batch, out, N, G);
}

// Round 9
// 495.178 us; speedup vs baseline: 1.1496x; 1.1237x over previous
//
#include <hip/hip_runtime.h>
#include <math.h>

#define EPS 1e-5f
#define PS 8  // pool slices per group
#define SW(row) (((row) & 7) << 4)   // XOR swizzle, 16B granularity

typedef __attribute__((ext_vector_type(8))) short short8;
typedef __attribute__((ext_vector_type(4))) float f32x4;

__device__ __forceinline__ float bf2f(unsigned short u) {
  union { unsigned i; float f; } c; c.i = ((unsigned)u) << 16; return c.f;
}
__device__ __forceinline__ float bflo(unsigned u) {
  union { unsigned i; float f; } c; c.i = u << 16; return c.f;
}
__device__ __forceinline__ float bfhi(unsigned u) {
  union { unsigned i; float f; } c; c.i = u & 0xFFFF0000u; return c.f;
}
__device__ __forceinline__ unsigned short f2bf(float f) {
  union { float f; unsigned i; } c; c.f = f;
  unsigned r = c.i + 0x7FFF + ((c.i >> 16) & 1);
  return (unsigned short)(r >> 16);
}

// ---------------------------------------------------------------------------
// Embed GEMM (K=128), LDS-staged: hb = relu(xb @ W^T + bias) bf16 (+score).
// BM=64, 4 waves 2x2 (wave tile 32x64). A,W staged via reg->ds_write with
// XOR swizzle; MFMA reads ds_read_b128 conflict-free.
// ---------------------------------------------------------------------------
template <bool SCORE>
__global__ __launch_bounds__(256, 2) void embed_gemm(
    const ushort* __restrict__ A,     // xb [M][128] bf16
    const ushort* __restrict__ W,     // [128][128] bf16
    const float* __restrict__ bias,
    const float* __restrict__ Wsc, const float* __restrict__ bsc,
    ushort* __restrict__ hb, float* __restrict__ scores, int M) {
  __shared__ __align__(16) ushort As[64 * 128];    // 16 KB, row 256 B
  __shared__ __align__(16) ushort Ws[128 * 128];   // 32 KB, row 256 B
  __shared__ float lds3[64][2];

  const int t = threadIdx.x;
  const int lane = t & 63;
  const int w = t >> 6;
  const int wm = w >> 1, wn = w & 1;
  const int m0 = blockIdx.x * 64;
  const int l15 = lane & 15, l16 = lane >> 4;

  // stage: A 1024 chunks (4/thread), W 2048 chunks (8/thread)
  short8 ar[4], wr_[8];
#pragma unroll
  for (int it = 0; it < 4; ++it) {
    int chunk = it * 256 + t;
    int row = chunk >> 4;           // 16 chunks per 256B row
    int b16 = chunk & 15;
    int grow = m0 + row; if (grow >= M) grow = M - 1;
    ar[it] = *(const short8*)(A + (size_t)grow * 128 + b16 * 8);
  }
#pragma unroll
  for (int it = 0; it < 8; ++it) {
    int chunk = it * 256 + t;
    int row = chunk >> 4;
    int b16 = chunk & 15;
    wr_[it] = *(const short8*)(W + (size_t)row * 128 + b16 * 8);
  }
#pragma unroll
  for (int it = 0; it < 4; ++it) {
    int chunk = it * 256 + t;
    int row = chunk >> 4, b = (chunk & 15) * 16;
    *(short8*)((char*)As + row * 256 + (b ^ SW(row))) = ar[it];
  }
#pragma unroll
  for (int it = 0; it < 8; ++it) {
    int chunk = it * 256 + t;
    int row = chunk >> 4, b = (chunk & 15) * 16;
    *(short8*)((char*)Ws + row * 256 + (b ^ SW(row))) = wr_[it];
  }
  __syncthreads();

  f32x4 acc[2][4];
#pragma unroll
  for (int i = 0; i < 2; ++i)
#pragma unroll
    for (int j = 0; j < 4; ++j) acc[i][j] = (f32x4){0.f, 0.f, 0.f, 0.f};

#pragma unroll
  for (int kk = 0; kk < 4; ++kk) {
    int cb = kk * 64 + l16 * 16;
    short8 a[2], b[4];
#pragma unroll
    for (int i = 0; i < 2; ++i) {
      int row = wm * 32 + i * 16 + l15;
      a[i] = *(const short8*)((const char*)As + row * 256 + (cb ^ SW(row)));
    }
#pragma unroll
    for (int j = 0; j < 4; ++j) {
      int row = wn * 64 + j * 16 + l15;
      b[j] = *(const short8*)((const char*)Ws + row * 256 + (cb ^ SW(row)));
    }
#pragma unroll
    for (int i = 0; i < 2; ++i)
#pragma unroll
      for (int j = 0; j < 4; ++j)
        acc[i][j] = __builtin_amdgcn_mfma_f32_16x16x32_bf16(a[i], b[j], acc[i][j], 0, 0, 0);
  }

  // epilogue: relu + hb store + optional score
#pragma unroll
  for (int i = 0; i < 2; ++i)
#pragma unroll
    for (int r = 0; r < 4; ++r) {
      int row = m0 + wm * 32 + i * 16 + l16 * 4 + r;
      bool valid = row < M;
      float psc = 0.f;
#pragma unroll
      for (int j = 0; j < 4; ++j) {
        int colw = wn * 64 + j * 16 + l15;
        float v = acc[i][j][r] + bias[colw];
        v = fmaxf(v, 0.f);
        if (valid) hb[(size_t)row * 128 + colw] = f2bf(v);
        if (SCORE) psc += v * Wsc[colw];
      }
      if (SCORE) {
#pragma unroll
        for (int mm = 1; mm <= 8; mm <<= 1) psc += __shfl_xor(psc, mm, 64);
        if (l15 == 0) lds3[wm * 32 + i * 16 + l16 * 4 + r][wn] = psc;
      }
    }
  if (SCORE) {
    __syncthreads();
    if (wn == 0 && l15 == 0) {
#pragma unroll
      for (int i = 0; i < 2; ++i)
#pragma unroll
        for (int r = 0; r < 4; ++r) {
          int rl = wm * 32 + i * 16 + l16 * 4 + r;
          int row = blockIdx.x * 64 + rl;
          if (row < M) scores[row] = lds3[rl][0] + lds3[rl][1] + bsc[0];
        }
    }
  }
}

// ---------------------------------------------------------------------------
// Layer GEMM (K=384), LDS-staged in two K-halves of 192:
// z = [hb | uv] @ Wbig^T + biasc; LayerNorm; relu; += hb residual (bf16 state);
// writes hb (+ next-layer score). BM=64, 4 waves 2x2 (wave tile 32x64).
// LDS: As 24 KB + Ws 48 KB (XOR swizzle) = 72 KB -> 2 blocks/CU.
// ---------------------------------------------------------------------------
template <bool SCORE>
__global__ __launch_bounds__(256, 2) void layer_gemm(
    const ushort* __restrict__ A0,    // hb [M][128]
    const ushort* __restrict__ A1,    // uv [M][256]
    const ushort* __restrict__ W,     // Wbig [128][384]
    const float* __restrict__ bias,
    const float* __restrict__ gamma, const float* __restrict__ beta,
    const float* __restrict__ Wsc, const float* __restrict__ bsc,
    ushort* __restrict__ hb, float* __restrict__ scores, int M) {
  __shared__ __align__(16) ushort As[64 * 192];    // 24 KB, row 384 B
  __shared__ __align__(16) ushort Ws[128 * 192];   // 48 KB, row 384 B
  __shared__ float lds1[64][2];
  __shared__ float lds2[64][2];
  __shared__ float lds3[64][2];

  const int t = threadIdx.x;
  const int lane = t & 63;
  const int w = t >> 6;
  const int wm = w >> 1, wn = w & 1;
  const int m0 = blockIdx.x * 64;
  const int l15 = lane & 15, l16 = lane >> 4;

  f32x4 acc[2][4];
#pragma unroll
  for (int i = 0; i < 2; ++i)
#pragma unroll
    for (int j = 0; j < 4; ++j) acc[i][j] = (f32x4){0.f, 0.f, 0.f, 0.f};

#pragma unroll
  for (int hf = 0; hf < 2; ++hf) {
    // ---- bulk load to regs (independent burst; hides latency) ----
    short8 ar[6], wr_[12];
#pragma unroll
    for (int it = 0; it < 6; ++it) {
      int chunk = it * 256 + t;        // [0,1536): 64 rows x 24 chunks
      int row = chunk / 24;
      int b16 = chunk % 24;
      int ec = hf * 192 + b16 * 8;     // combined element col
      int grow = m0 + row; if (grow >= M) grow = M - 1;
      const ushort* src = (ec < 128) ? (A0 + (size_t)grow * 128 + ec)
                                     : (A1 + (size_t)grow * 256 + (ec - 128));
      ar[it] = *(const short8*)src;
    }
#pragma unroll
    for (int it = 0; it < 12; ++it) {
      int chunk = it * 256 + t;        // [0,3072): 128 rows x 24 chunks
      int row = chunk / 24;
      int b16 = chunk % 24;
      wr_[it] = *(const short8*)(W + (size_t)row * 384 + hf * 192 + b16 * 8);
    }
    __syncthreads();  // previous half's readers done before overwrite
#pragma unroll
    for (int it = 0; it < 6; ++it) {
      int chunk = it * 256 + t;
      int row = chunk / 24, b = (chunk % 24) * 16;
      *(short8*)((char*)As + row * 384 + (b ^ SW(row))) = ar[it];
    }
#pragma unroll
    for (int it = 0; it < 12; ++it) {
      int chunk = it * 256 + t;
      int row = chunk / 24, b = (chunk % 24) * 16;
      *(short8*)((char*)Ws + row * 384 + (b ^ SW(row))) = wr_[it];
    }
    __syncthreads();
    // ---- compute 6 ksteps ----
#pragma unroll
    for (int kk = 0; kk < 6; ++kk) {
      int cb = kk * 64 + l16 * 16;
      short8 a[2], b[4];
#pragma unroll
      for (int i = 0; i < 2; ++i) {
        int row = wm * 32 + i * 16 + l15;
        a[i] = *(const short8*)((const char*)As + row * 384 + (cb ^ SW(row)));
      }
#pragma unroll
      for (int j = 0; j < 4; ++j) {
        int row = wn * 64 + j * 16 + l15;
        b[j] = *(const short8*)((const char*)Ws + row * 384 + (cb ^ SW(row)));
      }
#pragma unroll
      for (int i = 0; i < 2; ++i)
#pragma unroll
        for (int j = 0; j < 4; ++j)
          acc[i][j] = __builtin_amdgcn_mfma_f32_16x16x32_bf16(a[i], b[j], acc[i][j], 0, 0, 0);
    }
  }

  // ---- epilogue: bias + LN stats (pass 1) ----
#pragma unroll
  for (int i = 0; i < 2; ++i)
#pragma unroll
    for (int r = 0; r < 4; ++r) {
      float p1 = 0.f, p2 = 0.f;
#pragma unroll
      for (int j = 0; j < 4; ++j) {
        int colw = wn * 64 + j * 16 + l15;
        float v = acc[i][j][r] + bias[colw];
        acc[i][j][r] = v;
        p1 += v;
        p2 += v * v;
      }
#pragma unroll
      for (int mm = 1; mm <= 8; mm <<= 1) {
        p1 += __shfl_xor(p1, mm, 64);
        p2 += __shfl_xor(p2, mm, 64);
      }
      if (l15 == 0) {
        int rl = wm * 32 + i * 16 + l16 * 4 + r;
        lds1[rl][wn] = p1;
        lds2[rl][wn] = p2;
      }
    }
  __syncthreads();
  // ---- pass 2: normalize + relu + residual(bf16, L2-hot) + store ----
#pragma unroll
  for (int i = 0; i < 2; ++i)
#pragma unroll
    for (int r = 0; r < 4; ++r) {
      int rl = wm * 32 + i * 16 + l16 * 4 + r;
      int row = m0 + rl;
      bool valid = row < M;
      float s1 = lds1[rl][0] + lds1[rl][1];
      float s2 = lds2[rl][0] + lds2[rl][1];
      float mu = s1 * (1.f / 128.f);
      float var = s2 * (1.f / 128.f) - mu * mu;
      float rs = rsqrtf(var + EPS);
      float psc = 0.f;
#pragma unroll
      for (int j = 0; j < 4; ++j) {
        int colw = wn * 64 + j * 16 + l15;
        float v = acc[i][j][r];
        float o = (v - mu) * rs * gamma[colw] + beta[colw];
        o = fmaxf(o, 0.f);
        float res = o;
        if (valid) {
          res = o + bf2f(hb[(size_t)row * 128 + colw]);
          hb[(size_t)row * 128 + colw] = f2bf(res);
        }
        if (SCORE) psc += res * Wsc[colw];
      }
      if (SCORE) {
#pragma unroll
        for (int mm = 1; mm <= 8; mm <<= 1) psc += __shfl_xor(psc, mm, 64);
        if (l15 == 0) lds3[rl][wn] = psc;
      }
    }
  if (SCORE) {
    __syncthreads();
    if (wn == 0 && l15 == 0) {
#pragma unroll
      for (int i = 0; i < 2; ++i)
#pragma unroll
        for (int r = 0; r < 4; ++r) {
          int rl = wm * 32 + i * 16 + l16 * 4 + r;
          int row = m0 + rl;
          if (row < M) scores[row] = lds3[rl][0] + lds3[rl][1] + bsc[0];
        }
    }
  }
}

// ---------------------------------------------------------------------------
// Weight precompute: Wbig[l][:, p*128:(p+1)*128] = Wcomb[l][:,p-part] @ Wp[l]
// ---------------------------------------------------------------------------
__global__ __launch_bounds__(256) void wpre_kernel(
    const float* __restrict__ Wcomb, const float* __restrict__ Wself,
    const float* __restrict__ Wfwd, const float* __restrict__ Wbwd,
    ushort* __restrict__ Wbig) {
  const int l = blockIdx.x / 3, p = blockIdx.x % 3;
  const float* Wc = Wcomb + (size_t)l * 128 * 384;
  const float* Wp = (p == 0 ? Wself : (p == 1 ? Wfwd : Wbwd)) + (size_t)l * 128 * 128;
  __shared__ float Bs[128][132];
  const int t = threadIdx.x;
  for (int i = t; i < 16384; i += 256) Bs[i >> 7][i & 127] = Wp[i];
  __syncthreads();
  const int r = t >> 1;
  const int c0 = (t & 1) * 64;
  float acc[64];
#pragma unroll
  for (int c = 0; c < 64; ++c) acc[c] = 0.f;
  for (int k = 0; k < 128; ++k) {
    float a = Wc[(size_t)r * 384 + p * 128 + k];
#pragma unroll
    for (int c4 = 0; c4 < 16; ++c4) {
      float4 b4 = *(const float4*)&Bs[k][c0 + c4 * 4];
      acc[c4 * 4 + 0] = fmaf(a, b4.x, acc[c4 * 4 + 0]);
      acc[c4 * 4 + 1] = fmaf(a, b4.y, acc[c4 * 4 + 1]);
      acc[c4 * 4 + 2] = fmaf(a, b4.z, acc[c4 * 4 + 2]);
      acc[c4 * 4 + 3] = fmaf(a, b4.w, acc[c4 * 4 + 3]);
    }
  }
  ushort* o = Wbig + (size_t)l * 128 * 384 + (size_t)r * 384 + p * 128 + c0;
#pragma unroll
  for (int c = 0; c < 64; ++c) o[c] = f2bf(acc[c]);
}

// bias_c[l][c] = bcomb[l][c] + sum_k Wcomb[l][c][k] * bself[l][k]
__global__ void bpre_kernel(const float* __restrict__ Wcomb, const float* __restrict__ bself,
                            const float* __restrict__ bcomb, float* __restrict__ biasc, int L) {
  int idx = blockIdx.x * 128 + threadIdx.x;
  if (idx >= L * 128) return;
  int l = idx >> 7;
  const float* Wc = Wcomb + (size_t)l * 128 * 384 + (size_t)(idx & 127) * 384;
  const float* bs = bself + (size_t)l * 128;
  float acc = bcomb[idx];
  for (int k = 0; k < 128; ++k) acc = fmaf(Wc[k], bs[k], acc);
  biasc[idx] = acc;
}

// fp32 -> bf16 (n4 float4 groups)
__global__ void f2b_kernel(const float* __restrict__ in, ushort* __restrict__ out, int n4) {
  int i = blockIdx.x * 256 + threadIdx.x;
  if (i < n4) {
    float4 v = ((const float4*)in)[i];
    ushort4 o;
    o.x = f2bf(v.x); o.y = f2bf(v.y); o.z = f2bf(v.z); o.w = f2bf(v.w);
    ((ushort4*)out)[i] = o;
  }
}

// ---------------------------------------------------------------------------
// CSR build: histogram -> scan -> scatter (counting sort by dst)
// ---------------------------------------------------------------------------
__global__ void hist_kernel(const int* __restrict__ dst, int* __restrict__ counts, int E) {
  int e = blockIdx.x * 256 + threadIdx.x;
  if (e < E) atomicAdd(&counts[dst[e]], 1);
}

__global__ __launch_bounds__(256) void scan1_kernel(
    const int* __restrict__ c, int* __restrict__ ex, int* __restrict__ partials, int n) {
  __shared__ int sd[256];
  int t = threadIdx.x, b = blockIdx.x;
  int base = b * 1024 + t * 4;
  int v0 = (base + 0 < n) ? c[base + 0] : 0;
  int v1 = (base + 1 < n) ? c[base + 1] : 0;
  int v2 = (base + 2 < n) ? c[base + 2] : 0;
  int v3 = (base + 3 < n) ? c[base + 3] : 0;
  int tot = v0 + v1 + v2 + v3;
  sd[t] = tot;
  __syncthreads();
  for (int off = 1; off < 256; off <<= 1) {
    int x = (t >= off) ? sd[t - off] : 0;
    __syncthreads();
    sd[t] += x;
    __syncthreads();
  }
  int p = sd[t] - tot;
  if (base + 0 < n) ex[base + 0] = p;
  if (base + 1 < n) ex[base + 1] = p + v0;
  if (base + 2 < n) ex[base + 2] = p + v0 + v1;
  if (base + 3 < n) ex[base + 3] = p + v0 + v1 + v2;
  if (t == 255) partials[b] = sd[255];
}

__global__ __launch_bounds__(256) void scan2_kernel(int* __restrict__ partials, int nb) {
  __shared__ int sd[256];
  int t = threadIdx.x;
  int v = (t < nb) ? partials[t] : 0;
  sd[t] = v;
  __syncthreads();
  for (int off = 1; off < 256; off <<= 1) {
    int x = (t >= off) ? sd[t - off] : 0;
    __syncthreads();
    sd[t] += x;
    __syncthreads();
  }
  if (t < nb) partials[t] = sd[t] - v;
}

__global__ void scan3_kernel(const int* __restrict__ ex, const int* __restrict__ partials,
                             int* __restrict__ indptr, int n, int E) {
  int i = blockIdx.x * 256 + threadIdx.x;
  if (i < n) indptr[i] = ex[i] + partials[i >> 10];
  if (i == 0) indptr[n] = E;
}

__global__ void scatter_kernel(const int* __restrict__ ei, int* __restrict__ cursor,
                               int* __restrict__ ssrc, int E) {
  int e = blockIdx.x * 256 + threadIdx.x;
  if (e >= E) return;
  int s = ei[e];
  int d = ei[E + e];
  int pos = atomicAdd(&cursor[d], 1);
  ssrc[pos] = s;
}

// ---------------------------------------------------------------------------
// Edge aggregation: 1 wave/node. Lane-parallel prefetch of up to 64 edges'
// (src, alpha); inner loop broadcasts (s,alpha) and streams independent
// 256B row loads. u = sum al*h[s]; v = sum h[s] - u. uv[N][256] bf16.
// ---------------------------------------------------------------------------
__global__ __launch_bounds__(256) void aggr_kernel(
    const int* __restrict__ indptr, const int* __restrict__ ssrc,
    const float* __restrict__ scores, const ushort* __restrict__ hb,
    ushort* __restrict__ uv, int Nn) {
  int node = blockIdx.x * 4 + (threadIdx.x >> 6);
  if (node >= Nn) return;
  int lane = threadIdx.x & 63;
  int beg = indptr[node], end = indptr[node + 1];
  float si = scores[node];
  float u0 = 0.f, u1 = 0.f, t0 = 0.f, t1 = 0.f;
  for (int ebase = beg; ebase < end; ebase += 64) {
    int cnt = min(64, end - ebase);
    int sv = 0;
    float al = 0.f;
    if (lane < cnt) {
      sv = ssrc[ebase + lane];
      al = 1.f / (1.f + __expf(si - scores[sv]));  // sigmoid(scores[s]-si)
    }
    for (int e = 0; e < cnt; ++e) {
      int s_e = __shfl(sv, e, 64);
      float a_e = __shfl(al, e, 64);
      unsigned vv = *(const unsigned*)(hb + (size_t)s_e * 128 + lane * 2);
      float f0 = bflo(vv), f1 = bfhi(vv);
      u0 = fmaf(a_e, f0, u0);
      u1 = fmaf(a_e, f1, u1);
      t0 += f0;
      t1 += f1;
    }
  }
  unsigned pu = (unsigned)f2bf(u0) | ((unsigned)f2bf(u1) << 16);
  unsigned pv = (unsigned)f2bf(t0 - u0) | ((unsigned)f2bf(t1 - u1) << 16);
  *(unsigned*)(uv + (size_t)node * 256 + lane * 2) = pu;
  *(unsigned*)(uv + (size_t)node * 256 + 128 + lane * 2) = pv;
}

// ---------------------------------------------------------------------------
// Global mean pool over hb (bf16 state; batch sorted): two-stage, no atomics.
// ---------------------------------------------------------------------------
__global__ __launch_bounds__(128) void pool_stage_kernel(
    const ushort* __restrict__ hb, const int* __restrict__ batch,
    float* __restrict__ partial, int M) {
  int g = blockIdx.x, s = blockIdx.y, d = threadIdx.x;
  int lo = 0, hi = M;
  while (lo < hi) { int mid = (lo + hi) >> 1; if (batch[mid] < g) lo = mid + 1; else hi = mid; }
  int b0 = lo;
  hi = M;
  while (lo < hi) { int mid = (lo + hi) >> 1; if (batch[mid] <= g) lo = mid + 1; else hi = mid; }
  int b1 = lo;
  int len = b1 - b0;
  int chunk = (len + PS - 1) / PS;
  int r0 = b0 + s * chunk;
  int r1 = min(b1, r0 + chunk);
  float acc = 0.f;
  for (int i = r0; i < r1; ++i) acc += bf2f(hb[(size_t)i * 128 + d]);
  partial[((size_t)g * PS + s) * 128 + d] = acc;
}

__global__ void pool_final_kernel(const float* __restrict__ partial,
                                  const int* __restrict__ batch,
                                  float* __restrict__ out, int M, int G) {
  int idx = blockIdx.x * 256 + threadIdx.x;
  if (idx >= G * 128) return;
  int g = idx >> 7, d = idx & 127;
  float acc = 0.f;
#pragma unroll
  for (int s = 0; s < PS; ++s) acc += partial[((size_t)g * PS + s) * 128 + d];
  int lo = 0, hi = M;
  while (lo < hi) { int mid = (lo + hi) >> 1; if (batch[mid] < g) lo = mid + 1; else hi = mid; }
  int b0 = lo;
  hi = M;
  while (lo < hi) { int mid = (lo + hi) >> 1; if (batch[mid] <= g) lo = mid + 1; else hi = mid; }
  int c = lo - b0;
  out[idx] = acc / (float)(c > 0 ? c : 1);
}

// ---------------------------------------------------------------------------
extern "C" void kernel_launch(void* const* d_in, const int* in_sizes, int n_in,
                              void* d_out, int out_size, void* d_ws, size_t ws_size,
                              hipStream_t stream) {
  const float* x      = (const float*)d_in[0];
  const int*   ei     = (const int*)d_in[1];
  const int*   batch  = (const int*)d_in[2];
  const float* Wemb   = (const float*)d_in[3];
  const float* bemb   = (const float*)d_in[4];
  const float* Wscore = (const float*)d_in[5];
  const float* bscore = (const float*)d_in[6];
  const float* Wfwd   = (const float*)d_in[7];
  const float* Wbwd   = (const float*)d_in[8];
  const float* Wself  = (const float*)d_in[9];
  const float* bself  = (const float*)d_in[10];
  const float* Wcomb  = (const float*)d_in[11];
  const float* bcomb  = (const float*)d_in[12];
  const float* gamma  = (const float*)d_in[13];
  const float* beta   = (const float*)d_in[14];

  const int N = in_sizes[0] / 128;
  const int E = in_sizes[1] / 2;
  const int L = in_sizes[5] / 128;
  const int G = out_size / 128;
  float* out = (float*)d_out;

  char* p = (char*)d_ws;
  auto alloc = [&](size_t bytes) -> char* {
    char* r = p;
    p += (bytes + 255) & ~(size_t)255;
    return r;
  };
  ushort* xb     = (ushort*)alloc((size_t)N * 128 * 2);
  ushort* hb16   = (ushort*)alloc((size_t)N * 128 * 2);   // bf16 state (only state)
  ushort* uv     = (ushort*)alloc((size_t)N * 256 * 2);   // [u | v] bf16
  float*  scores = (float*)alloc((size_t)N * 4);
  ushort* Wemb_b = (ushort*)alloc(16384 * 2);
  ushort* Wbig   = (ushort*)alloc((size_t)L * 128 * 384 * 2);
  float*  biasc  = (float*)alloc((size_t)L * 128 * 4);
  int* counts    = (int*)alloc((size_t)N * 4);
  int* ex        = (int*)alloc((size_t)N * 4);
  int* partials  = (int*)alloc(1024);
  int* indptr    = (int*)alloc((size_t)(N + 1) * 4);
  int* cursor    = (int*)alloc((size_t)N * 4);
  int* ssrc      = (int*)alloc((size_t)E * 4);
  float* pool_p  = (float*)alloc((size_t)G * PS * 128 * 4);

  const int gb = (N + 63) / 64;

  // 0. precompute: conversions + combined weights
  f2b_kernel<<<(N * 32 + 255) / 256, 256, 0, stream>>>(x, xb, N * 32);
  f2b_kernel<<<16, 256, 0, stream>>>(Wemb, Wemb_b, 4096);
  wpre_kernel<<<3 * L, 256, 0, stream>>>(Wcomb, Wself, Wfwd, Wbwd, Wbig);
  bpre_kernel<<<L, 128, 0, stream>>>(Wcomb, bself, bcomb, biasc, L);

  // 1. CSR build (edges constant within a call)
  hipMemsetAsync(counts, 0, (size_t)N * 4, stream);
  hist_kernel<<<(E + 255) / 256, 256, 0, stream>>>(ei + E, counts, E);
  int nb = (N + 1023) / 1024;
  scan1_kernel<<<nb, 256, 0, stream>>>(counts, ex, partials, N);
  scan2_kernel<<<1, 256, 0, stream>>>(partials, nb);
  scan3_kernel<<<(N + 255) / 256, 256, 0, stream>>>(ex, partials, indptr, N, E);
  hipMemcpyAsync(cursor, indptr, (size_t)N * 4, hipMemcpyDeviceToDevice, stream);
  scatter_kernel<<<(E + 255) / 256, 256, 0, stream>>>(ei, cursor, ssrc, E);

  // 2. embedding: hb = relu(xb @ Wemb^T + bemb), fused layer-0 scores
  embed_gemm<true><<<gb, 256, 0, stream>>>(xb, Wemb_b, bemb, Wscore, bscore,
                                           hb16, scores, N);

  // 3. layers: aggr -> staged GEMM+LN+residual(+next scores)
  for (int l = 0; l < L; ++l) {
    aggr_kernel<<<(N + 3) / 4, 256, 0, stream>>>(indptr, ssrc, scores, hb16, uv, N);
    if (l < L - 1) {
      layer_gemm<true><<<gb, 256, 0, stream>>>(
          hb16, uv, Wbig + (size_t)l * 128 * 384, biasc + (size_t)l * 128,
          gamma + (size_t)l * 128, beta + (size_t)l * 128,
          Wscore + (size_t)(l + 1) * 128, bscore + (l + 1), hb16, scores, N);
    } else {
      layer_gemm<false><<<gb, 256, 0, stream>>>(
          hb16, uv, Wbig + (size_t)l * 128 * 384, biasc + (size_t)l * 128,
          gamma + (size_t)l * 128, beta + (size_t)l * 128,
          nullptr, nullptr, hb16, scores, N);
    }
  }

  // 4. global mean pool (two-stage, no atomics)
  pool_stage_kernel<<<dim3(G, PS), 128, 0, stream>>>(hb16, batch, pool_p, N);
  pool_final_kernel<<<(G * 128 + 255) / 256, 256, 0, stream>>>(pool_p, batch, out, N, G);
}

// Round 10
// 432.970 us; speedup vs baseline: 1.3148x; 1.1437x over previous
//
#include <hip/hip_runtime.h>
#include <math.h>

#define EPS 1e-5f
#define PS 8  // pool slices per group
#define SW(row) (((row) & 7) << 4)   // XOR swizzle, 16B granularity

typedef __attribute__((ext_vector_type(8))) short short8;
typedef __attribute__((ext_vector_type(4))) float f32x4;

__device__ __forceinline__ float bf2f(unsigned short u) {
  union { unsigned i; float f; } c; c.i = ((unsigned)u) << 16; return c.f;
}
__device__ __forceinline__ float bflo(unsigned u) {
  union { unsigned i; float f; } c; c.i = u << 16; return c.f;
}
__device__ __forceinline__ float bfhi(unsigned u) {
  union { unsigned i; float f; } c; c.i = u & 0xFFFF0000u; return c.f;
}
__device__ __forceinline__ unsigned short f2bf(float f) {
  union { float f; unsigned i; } c; c.f = f;
  unsigned r = c.i + 0x7FFF + ((c.i >> 16) & 1);
  return (unsigned short)(r >> 16);
}

// ---------------------------------------------------------------------------
// Embed GEMM (K=128), LDS-staged: hb = relu(x_f32 @ W^T + bias) bf16 (+score).
// BM=64, 4 waves 2x2 (wave tile 32x64). A read fp32 + converted in-register
// during staging; W bf16. XOR-swizzled LDS; ds_read_b128 conflict-free.
// ---------------------------------------------------------------------------
template <bool SCORE>
__global__ __launch_bounds__(256, 2) void embed_gemm(
    const float* __restrict__ X,      // x [M][128] fp32
    const ushort* __restrict__ W,     // [128][128] bf16
    const float* __restrict__ bias,
    const float* __restrict__ Wsc, const float* __restrict__ bsc,
    ushort* __restrict__ hb, float* __restrict__ scores, int M) {
  __shared__ __align__(16) ushort As[64 * 128];    // 16 KB, row 256 B
  __shared__ __align__(16) ushort Ws[128 * 128];   // 32 KB, row 256 B
  __shared__ float lds3[64][2];

  const int t = threadIdx.x;
  const int lane = t & 63;
  const int w = t >> 6;
  const int wm = w >> 1, wn = w & 1;
  const int m0 = blockIdx.x * 64;
  const int l15 = lane & 15, l16 = lane >> 4;

  // stage: A 1024 chunks (4/thread, fp32->bf16), W 2048 chunks (8/thread)
  short8 ar[4], wr_[8];
#pragma unroll
  for (int it = 0; it < 4; ++it) {
    int chunk = it * 256 + t;
    int row = chunk >> 4;           // 16 chunks per 256B row
    int b16 = chunk & 15;
    int grow = m0 + row; if (grow >= M) grow = M - 1;
    const float* xr = X + (size_t)grow * 128 + b16 * 8;
    float4 f0 = *(const float4*)xr;
    float4 f1 = *(const float4*)(xr + 4);
    short8 v;
    v[0] = (short)f2bf(f0.x); v[1] = (short)f2bf(f0.y);
    v[2] = (short)f2bf(f0.z); v[3] = (short)f2bf(f0.w);
    v[4] = (short)f2bf(f1.x); v[5] = (short)f2bf(f1.y);
    v[6] = (short)f2bf(f1.z); v[7] = (short)f2bf(f1.w);
    ar[it] = v;
  }
#pragma unroll
  for (int it = 0; it < 8; ++it) {
    int chunk = it * 256 + t;
    int row = chunk >> 4;
    int b16 = chunk & 15;
    wr_[it] = *(const short8*)(W + (size_t)row * 128 + b16 * 8);
  }
#pragma unroll
  for (int it = 0; it < 4; ++it) {
    int chunk = it * 256 + t;
    int row = chunk >> 4, b = (chunk & 15) * 16;
    *(short8*)((char*)As + row * 256 + (b ^ SW(row))) = ar[it];
  }
#pragma unroll
  for (int it = 0; it < 8; ++it) {
    int chunk = it * 256 + t;
    int row = chunk >> 4, b = (chunk & 15) * 16;
    *(short8*)((char*)Ws + row * 256 + (b ^ SW(row))) = wr_[it];
  }
  __syncthreads();

  f32x4 acc[2][4];
#pragma unroll
  for (int i = 0; i < 2; ++i)
#pragma unroll
    for (int j = 0; j < 4; ++j) acc[i][j] = (f32x4){0.f, 0.f, 0.f, 0.f};

#pragma unroll
  for (int kk = 0; kk < 4; ++kk) {
    int cb = kk * 64 + l16 * 16;
    short8 a[2], b[4];
#pragma unroll
    for (int i = 0; i < 2; ++i) {
      int row = wm * 32 + i * 16 + l15;
      a[i] = *(const short8*)((const char*)As + row * 256 + (cb ^ SW(row)));
    }
#pragma unroll
    for (int j = 0; j < 4; ++j) {
      int row = wn * 64 + j * 16 + l15;
      b[j] = *(const short8*)((const char*)Ws + row * 256 + (cb ^ SW(row)));
    }
#pragma unroll
    for (int i = 0; i < 2; ++i)
#pragma unroll
      for (int j = 0; j < 4; ++j)
        acc[i][j] = __builtin_amdgcn_mfma_f32_16x16x32_bf16(a[i], b[j], acc[i][j], 0, 0, 0);
  }

  // epilogue: relu + hb store + optional score
#pragma unroll
  for (int i = 0; i < 2; ++i)
#pragma unroll
    for (int r = 0; r < 4; ++r) {
      int row = m0 + wm * 32 + i * 16 + l16 * 4 + r;
      bool valid = row < M;
      float psc = 0.f;
#pragma unroll
      for (int j = 0; j < 4; ++j) {
        int colw = wn * 64 + j * 16 + l15;
        float v = acc[i][j][r] + bias[colw];
        v = fmaxf(v, 0.f);
        if (valid) hb[(size_t)row * 128 + colw] = f2bf(v);
        if (SCORE) psc += v * Wsc[colw];
      }
      if (SCORE) {
#pragma unroll
        for (int mm = 1; mm <= 8; mm <<= 1) psc += __shfl_xor(psc, mm, 64);
        if (l15 == 0) lds3[wm * 32 + i * 16 + l16 * 4 + r][wn] = psc;
      }
    }
  if (SCORE) {
    __syncthreads();
    if (wn == 0 && l15 == 0) {
#pragma unroll
      for (int i = 0; i < 2; ++i)
#pragma unroll
        for (int r = 0; r < 4; ++r) {
          int rl = wm * 32 + i * 16 + l16 * 4 + r;
          int row = blockIdx.x * 64 + rl;
          if (row < M) scores[row] = lds3[rl][0] + lds3[rl][1] + bsc[0];
        }
    }
  }
}

// ---------------------------------------------------------------------------
// Layer GEMM (K=384), LDS-staged in two K-halves of 192:
// z = [hb | uv] @ Wbig^T + biasc; LayerNorm; relu; += hb residual (bf16 state);
// writes hb (+ next-layer score). BM=64, 4 waves 2x2 (wave tile 32x64).
// LDS: As 24 KB + Ws 48 KB (XOR swizzle) = 72 KB -> 2 blocks/CU.
// ---------------------------------------------------------------------------
template <bool SCORE>
__global__ __launch_bounds__(256, 2) void layer_gemm(
    const ushort* __restrict__ A0,    // hb [M][128]
    const ushort* __restrict__ A1,    // uv [M][256]
    const ushort* __restrict__ W,     // Wbig [128][384]
    const float* __restrict__ bias,
    const float* __restrict__ gamma, const float* __restrict__ beta,
    const float* __restrict__ Wsc, const float* __restrict__ bsc,
    ushort* __restrict__ hb, float* __restrict__ scores, int M) {
  __shared__ __align__(16) ushort As[64 * 192];    // 24 KB, row 384 B
  __shared__ __align__(16) ushort Ws[128 * 192];   // 48 KB, row 384 B
  __shared__ float lds1[64][2];
  __shared__ float lds2[64][2];
  __shared__ float lds3[64][2];

  const int t = threadIdx.x;
  const int lane = t & 63;
  const int w = t >> 6;
  const int wm = w >> 1, wn = w & 1;
  const int m0 = blockIdx.x * 64;
  const int l15 = lane & 15, l16 = lane >> 4;

  f32x4 acc[2][4];
#pragma unroll
  for (int i = 0; i < 2; ++i)
#pragma unroll
    for (int j = 0; j < 4; ++j) acc[i][j] = (f32x4){0.f, 0.f, 0.f, 0.f};

#pragma unroll
  for (int hf = 0; hf < 2; ++hf) {
    // ---- bulk load to regs (independent burst; hides latency) ----
    short8 ar[6], wr_[12];
#pragma unroll
    for (int it = 0; it < 6; ++it) {
      int chunk = it * 256 + t;        // [0,1536): 64 rows x 24 chunks
      int row = chunk / 24;
      int b16 = chunk % 24;
      int ec = hf * 192 + b16 * 8;     // combined element col
      int grow = m0 + row; if (grow >= M) grow = M - 1;
      const ushort* src = (ec < 128) ? (A0 + (size_t)grow * 128 + ec)
                                     : (A1 + (size_t)grow * 256 + (ec - 128));
      ar[it] = *(const short8*)src;
    }
#pragma unroll
    for (int it = 0; it < 12; ++it) {
      int chunk = it * 256 + t;        // [0,3072): 128 rows x 24 chunks
      int row = chunk / 24;
      int b16 = chunk % 24;
      wr_[it] = *(const short8*)(W + (size_t)row * 384 + hf * 192 + b16 * 8);
    }
    __syncthreads();  // previous half's readers done before overwrite
#pragma unroll
    for (int it = 0; it < 6; ++it) {
      int chunk = it * 256 + t;
      int row = chunk / 24, b = (chunk % 24) * 16;
      *(short8*)((char*)As + row * 384 + (b ^ SW(row))) = ar[it];
    }
#pragma unroll
    for (int it = 0; it < 12; ++it) {
      int chunk = it * 256 + t;
      int row = chunk / 24, b = (chunk % 24) * 16;
      *(short8*)((char*)Ws + row * 384 + (b ^ SW(row))) = wr_[it];
    }
    __syncthreads();
    // ---- compute 6 ksteps ----
#pragma unroll
    for (int kk = 0; kk < 6; ++kk) {
      int cb = kk * 64 + l16 * 16;
      short8 a[2], b[4];
#pragma unroll
      for (int i = 0; i < 2; ++i) {
        int row = wm * 32 + i * 16 + l15;
        a[i] = *(const short8*)((const char*)As + row * 384 + (cb ^ SW(row)));
      }
#pragma unroll
      for (int j = 0; j < 4; ++j) {
        int row = wn * 64 + j * 16 + l15;
        b[j] = *(const short8*)((const char*)Ws + row * 384 + (cb ^ SW(row)));
      }
#pragma unroll
      for (int i = 0; i < 2; ++i)
#pragma unroll
        for (int j = 0; j < 4; ++j)
          acc[i][j] = __builtin_amdgcn_mfma_f32_16x16x32_bf16(a[i], b[j], acc[i][j], 0, 0, 0);
    }
  }

  // ---- epilogue: bias + LN stats (pass 1) ----
#pragma unroll
  for (int i = 0; i < 2; ++i)
#pragma unroll
    for (int r = 0; r < 4; ++r) {
      float p1 = 0.f, p2 = 0.f;
#pragma unroll
      for (int j = 0; j < 4; ++j) {
        int colw = wn * 64 + j * 16 + l15;
        float v = acc[i][j][r] + bias[colw];
        acc[i][j][r] = v;
        p1 += v;
        p2 += v * v;
      }
#pragma unroll
      for (int mm = 1; mm <= 8; mm <<= 1) {
        p1 += __shfl_xor(p1, mm, 64);
        p2 += __shfl_xor(p2, mm, 64);
      }
      if (l15 == 0) {
        int rl = wm * 32 + i * 16 + l16 * 4 + r;
        lds1[rl][wn] = p1;
        lds2[rl][wn] = p2;
      }
    }
  __syncthreads();
  // ---- pass 2: normalize + relu + residual(bf16, L2-hot) + store ----
#pragma unroll
  for (int i = 0; i < 2; ++i)
#pragma unroll
    for (int r = 0; r < 4; ++r) {
      int rl = wm * 32 + i * 16 + l16 * 4 + r;
      int row = m0 + rl;
      bool valid = row < M;
      float s1 = lds1[rl][0] + lds1[rl][1];
      float s2 = lds2[rl][0] + lds2[rl][1];
      float mu = s1 * (1.f / 128.f);
      float var = s2 * (1.f / 128.f) - mu * mu;
      float rs = rsqrtf(var + EPS);
      float psc = 0.f;
#pragma unroll
      for (int j = 0; j < 4; ++j) {
        int colw = wn * 64 + j * 16 + l15;
        float v = acc[i][j][r];
        float o = (v - mu) * rs * gamma[colw] + beta[colw];
        o = fmaxf(o, 0.f);
        float res = o;
        if (valid) {
          res = o + bf2f(hb[(size_t)row * 128 + colw]);
          hb[(size_t)row * 128 + colw] = f2bf(res);
        }
        if (SCORE) psc += res * Wsc[colw];
      }
      if (SCORE) {
#pragma unroll
        for (int mm = 1; mm <= 8; mm <<= 1) psc += __shfl_xor(psc, mm, 64);
        if (l15 == 0) lds3[rl][wn] = psc;
      }
    }
  if (SCORE) {
    __syncthreads();
    if (wn == 0 && l15 == 0) {
#pragma unroll
      for (int i = 0; i < 2; ++i)
#pragma unroll
        for (int r = 0; r < 4; ++r) {
          int rl = wm * 32 + i * 16 + l16 * 4 + r;
          int row = m0 + rl;
          if (row < M) scores[row] = lds3[rl][0] + lds3[rl][1] + bsc[0];
        }
    }
  }
}

// ---------------------------------------------------------------------------
// Weight precompute: Wbig[l][:, p*128:(p+1)*128] = Wcomb[l][:,p-part] @ Wp[l]
// ---------------------------------------------------------------------------
__global__ __launch_bounds__(256) void wpre_kernel(
    const float* __restrict__ Wcomb, const float* __restrict__ Wself,
    const float* __restrict__ Wfwd, const float* __restrict__ Wbwd,
    ushort* __restrict__ Wbig) {
  const int l = blockIdx.x / 3, p = blockIdx.x % 3;
  const float* Wc = Wcomb + (size_t)l * 128 * 384;
  const float* Wp = (p == 0 ? Wself : (p == 1 ? Wfwd : Wbwd)) + (size_t)l * 128 * 128;
  __shared__ float Bs[128][132];
  const int t = threadIdx.x;
  for (int i = t; i < 16384; i += 256) Bs[i >> 7][i & 127] = Wp[i];
  __syncthreads();
  const int r = t >> 1;
  const int c0 = (t & 1) * 64;
  float acc[64];
#pragma unroll
  for (int c = 0; c < 64; ++c) acc[c] = 0.f;
  for (int k = 0; k < 128; ++k) {
    float a = Wc[(size_t)r * 384 + p * 128 + k];
#pragma unroll
    for (int c4 = 0; c4 < 16; ++c4) {
      float4 b4 = *(const float4*)&Bs[k][c0 + c4 * 4];
      acc[c4 * 4 + 0] = fmaf(a, b4.x, acc[c4 * 4 + 0]);
      acc[c4 * 4 + 1] = fmaf(a, b4.y, acc[c4 * 4 + 1]);
      acc[c4 * 4 + 2] = fmaf(a, b4.z, acc[c4 * 4 + 2]);
      acc[c4 * 4 + 3] = fmaf(a, b4.w, acc[c4 * 4 + 3]);
    }
  }
  ushort* o = Wbig + (size_t)l * 128 * 384 + (size_t)r * 384 + p * 128 + c0;
#pragma unroll
  for (int c = 0; c < 64; ++c) o[c] = f2bf(acc[c]);
}

// bias_c[l][c] = bcomb[l][c] + sum_k Wcomb[l][c][k] * bself[l][k]
__global__ void bpre_kernel(const float* __restrict__ Wcomb, const float* __restrict__ bself,
                            const float* __restrict__ bcomb, float* __restrict__ biasc, int L) {
  int idx = blockIdx.x * 128 + threadIdx.x;
  if (idx >= L * 128) return;
  int l = idx >> 7;
  const float* Wc = Wcomb + (size_t)l * 128 * 384 + (size_t)(idx & 127) * 384;
  const float* bs = bself + (size_t)l * 128;
  float acc = bcomb[idx];
  for (int k = 0; k < 128; ++k) acc = fmaf(Wc[k], bs[k], acc);
  biasc[idx] = acc;
}

// fp32 -> bf16 (n4 float4 groups)
__global__ void f2b_kernel(const float* __restrict__ in, ushort* __restrict__ out, int n4) {
  int i = blockIdx.x * 256 + threadIdx.x;
  if (i < n4) {
    float4 v = ((const float4*)in)[i];
    ushort4 o;
    o.x = f2bf(v.x); o.y = f2bf(v.y); o.z = f2bf(v.z); o.w = f2bf(v.w);
    ((ushort4*)out)[i] = o;
  }
}

// ---------------------------------------------------------------------------
// CSR build: histogram -> scan -> scatter (counting sort by dst)
// ---------------------------------------------------------------------------
__global__ void hist_kernel(const int* __restrict__ dst, int* __restrict__ counts, int E) {
  int e = blockIdx.x * 256 + threadIdx.x;
  if (e < E) atomicAdd(&counts[dst[e]], 1);
}

__global__ __launch_bounds__(256) void scan1_kernel(
    const int* __restrict__ c, int* __restrict__ ex, int* __restrict__ partials, int n) {
  __shared__ int sd[256];
  int t = threadIdx.x, b = blockIdx.x;
  int base = b * 1024 + t * 4;
  int v0 = (base + 0 < n) ? c[base + 0] : 0;
  int v1 = (base + 1 < n) ? c[base + 1] : 0;
  int v2 = (base + 2 < n) ? c[base + 2] : 0;
  int v3 = (base + 3 < n) ? c[base + 3] : 0;
  int tot = v0 + v1 + v2 + v3;
  sd[t] = tot;
  __syncthreads();
  for (int off = 1; off < 256; off <<= 1) {
    int x = (t >= off) ? sd[t - off] : 0;
    __syncthreads();
    sd[t] += x;
    __syncthreads();
  }
  int p = sd[t] - tot;
  if (base + 0 < n) ex[base + 0] = p;
  if (base + 1 < n) ex[base + 1] = p + v0;
  if (base + 2 < n) ex[base + 2] = p + v0 + v1;
  if (base + 3 < n) ex[base + 3] = p + v0 + v1 + v2;
  if (t == 255) partials[b] = sd[255];
}

__global__ __launch_bounds__(256) void scan2_kernel(int* __restrict__ partials, int nb) {
  __shared__ int sd[256];
  int t = threadIdx.x;
  int v = (t < nb) ? partials[t] : 0;
  sd[t] = v;
  __syncthreads();
  for (int off = 1; off < 256; off <<= 1) {
    int x = (t >= off) ? sd[t - off] : 0;
    __syncthreads();
    sd[t] += x;
    __syncthreads();
  }
  if (t < nb) partials[t] = sd[t] - v;
}

__global__ void scan3_kernel(const int* __restrict__ ex, const int* __restrict__ partials,
                             int* __restrict__ indptr, int n, int E) {
  int i = blockIdx.x * 256 + threadIdx.x;
  if (i < n) indptr[i] = ex[i] + partials[i >> 10];
  if (i == 0) indptr[n] = E;
}

__global__ void scatter_kernel(const int* __restrict__ ei, int* __restrict__ cursor,
                               int* __restrict__ ssrc, int E) {
  int e = blockIdx.x * 256 + threadIdx.x;
  if (e >= E) return;
  int s = ei[e];
  int d = ei[E + e];
  int pos = atomicAdd(&cursor[d], 1);
  ssrc[pos] = s;
}

// ---------------------------------------------------------------------------
// Edge aggregation: 1 wave/node. Lane-parallel prefetch of up to 64 edges'
// (src, alpha); inner loop unrolled x4: 4 broadcasts + 4 independent 256B
// row loads in flight, then 16 FMAs. u = sum al*h[s]; v = sum h[s] - u.
// ---------------------------------------------------------------------------
__global__ __launch_bounds__(256) void aggr_kernel(
    const int* __restrict__ indptr, const int* __restrict__ ssrc,
    const float* __restrict__ scores, const ushort* __restrict__ hb,
    ushort* __restrict__ uv, int Nn) {
  int node = blockIdx.x * 4 + (threadIdx.x >> 6);
  if (node >= Nn) return;
  int lane = threadIdx.x & 63;
  int beg = indptr[node], end = indptr[node + 1];
  float si = scores[node];
  float u0 = 0.f, u1 = 0.f, t0 = 0.f, t1 = 0.f;
  for (int ebase = beg; ebase < end; ebase += 64) {
    int cnt = min(64, end - ebase);
    int sv = 0;
    float al = 0.f;
    if (lane < cnt) {
      sv = ssrc[ebase + lane];
      al = 1.f / (1.f + __expf(si - scores[sv]));  // sigmoid(scores[s]-si)
    }
    int e = 0;
    for (; e + 4 <= cnt; e += 4) {
      int s0 = __shfl(sv, e, 64),     s1 = __shfl(sv, e + 1, 64);
      int s2 = __shfl(sv, e + 2, 64), s3 = __shfl(sv, e + 3, 64);
      float a0 = __shfl(al, e, 64),     a1 = __shfl(al, e + 1, 64);
      float a2 = __shfl(al, e + 2, 64), a3 = __shfl(al, e + 3, 64);
      unsigned v0 = *(const unsigned*)(hb + (size_t)s0 * 128 + lane * 2);
      unsigned v1 = *(const unsigned*)(hb + (size_t)s1 * 128 + lane * 2);
      unsigned v2 = *(const unsigned*)(hb + (size_t)s2 * 128 + lane * 2);
      unsigned v3 = *(const unsigned*)(hb + (size_t)s3 * 128 + lane * 2);
      float f;
      f = bflo(v0); u0 = fmaf(a0, f, u0); t0 += f;
      f = bfhi(v0); u1 = fmaf(a0, f, u1); t1 += f;
      f = bflo(v1); u0 = fmaf(a1, f, u0); t0 += f;
      f = bfhi(v1); u1 = fmaf(a1, f, u1); t1 += f;
      f = bflo(v2); u0 = fmaf(a2, f, u0); t0 += f;
      f = bfhi(v2); u1 = fmaf(a2, f, u1); t1 += f;
      f = bflo(v3); u0 = fmaf(a3, f, u0); t0 += f;
      f = bfhi(v3); u1 = fmaf(a3, f, u1); t1 += f;
    }
    for (; e < cnt; ++e) {
      int s_e = __shfl(sv, e, 64);
      float a_e = __shfl(al, e, 64);
      unsigned vv = *(const unsigned*)(hb + (size_t)s_e * 128 + lane * 2);
      float f0 = bflo(vv), f1 = bfhi(vv);
      u0 = fmaf(a_e, f0, u0); t0 += f0;
      u1 = fmaf(a_e, f1, u1); t1 += f1;
    }
  }
  unsigned pu = (unsigned)f2bf(u0) | ((unsigned)f2bf(u1) << 16);
  unsigned pv = (unsigned)f2bf(t0 - u0) | ((unsigned)f2bf(t1 - u1) << 16);
  *(unsigned*)(uv + (size_t)node * 256 + lane * 2) = pu;
  *(unsigned*)(uv + (size_t)node * 256 + 128 + lane * 2) = pv;
}

// ---------------------------------------------------------------------------
// Global mean pool over hb (bf16 state; batch sorted): two-stage, no atomics.
// ---------------------------------------------------------------------------
__global__ __launch_bounds__(128) void pool_stage_kernel(
    const ushort* __restrict__ hb, const int* __restrict__ batch,
    float* __restrict__ partial, int M) {
  int g = blockIdx.x, s = blockIdx.y, d = threadIdx.x;
  int lo = 0, hi = M;
  while (lo < hi) { int mid = (lo + hi) >> 1; if (batch[mid] < g) lo = mid + 1; else hi = mid; }
  int b0 = lo;
  hi = M;
  while (lo < hi) { int mid = (lo + hi) >> 1; if (batch[mid] <= g) lo = mid + 1; else hi = mid; }
  int b1 = lo;
  int len = b1 - b0;
  int chunk = (len + PS - 1) / PS;
  int r0 = b0 + s * chunk;
  int r1 = min(b1, r0 + chunk);
  float acc = 0.f;
  for (int i = r0; i < r1; ++i) acc += bf2f(hb[(size_t)i * 128 + d]);
  partial[((size_t)g * PS + s) * 128 + d] = acc;
}

__global__ void pool_final_kernel(const float* __restrict__ partial,
                                  const int* __restrict__ batch,
                                  float* __restrict__ out, int M, int G) {
  int idx = blockIdx.x * 256 + threadIdx.x;
  if (idx >= G * 128) return;
  int g = idx >> 7, d = idx & 127;
  float acc = 0.f;
#pragma unroll
  for (int s = 0; s < PS; ++s) acc += partial[((size_t)g * PS + s) * 128 + d];
  int lo = 0, hi = M;
  while (lo < hi) { int mid = (lo + hi) >> 1; if (batch[mid] < g) lo = mid + 1; else hi = mid; }
  int b0 = lo;
  hi = M;
  while (lo < hi) { int mid = (lo + hi) >> 1; if (batch[mid] <= g) lo = mid + 1; else hi = mid; }
  int c = lo - b0;
  out[idx] = acc / (float)(c > 0 ? c : 1);
}

// ---------------------------------------------------------------------------
extern "C" void kernel_launch(void* const* d_in, const int* in_sizes, int n_in,
                              void* d_out, int out_size, void* d_ws, size_t ws_size,
                              hipStream_t stream) {
  const float* x      = (const float*)d_in[0];
  const int*   ei     = (const int*)d_in[1];
  const int*   batch  = (const int*)d_in[2];
  const float* Wemb   = (const float*)d_in[3];
  const float* bemb   = (const float*)d_in[4];
  const float* Wscore = (const float*)d_in[5];
  const float* bscore = (const float*)d_in[6];
  const float* Wfwd   = (const float*)d_in[7];
  const float* Wbwd   = (const float*)d_in[8];
  const float* Wself  = (const float*)d_in[9];
  const float* bself  = (const float*)d_in[10];
  const float* Wcomb  = (const float*)d_in[11];
  const float* bcomb  = (const float*)d_in[12];
  const float* gamma  = (const float*)d_in[13];
  const float* beta   = (const float*)d_in[14];

  const int N = in_sizes[0] / 128;
  const int E = in_sizes[1] / 2;
  const int L = in_sizes[5] / 128;
  const int G = out_size / 128;
  float* out = (float*)d_out;

  char* p = (char*)d_ws;
  auto alloc = [&](size_t bytes) -> char* {
    char* r = p;
    p += (bytes + 255) & ~(size_t)255;
    return r;
  };
  ushort* hb16   = (ushort*)alloc((size_t)N * 128 * 2);   // bf16 state (only state)
  ushort* uv     = (ushort*)alloc((size_t)N * 256 * 2);   // [u | v] bf16
  float*  scores = (float*)alloc((size_t)N * 4);
  ushort* Wemb_b = (ushort*)alloc(16384 * 2);
  ushort* Wbig   = (ushort*)alloc((size_t)L * 128 * 384 * 2);
  float*  biasc  = (float*)alloc((size_t)L * 128 * 4);
  int* counts    = (int*)alloc((size_t)N * 4);
  int* ex        = (int*)alloc((size_t)N * 4);
  int* partials  = (int*)alloc(1024);
  int* indptr    = (int*)alloc((size_t)(N + 1) * 4);
  int* cursor    = (int*)alloc((size_t)N * 4);
  int* ssrc      = (int*)alloc((size_t)E * 4);
  float* pool_p  = (float*)alloc((size_t)G * PS * 128 * 4);

  const int gb = (N + 63) / 64;

  // 0. precompute: conversions + combined weights
  f2b_kernel<<<16, 256, 0, stream>>>(Wemb, Wemb_b, 4096);
  wpre_kernel<<<3 * L, 256, 0, stream>>>(Wcomb, Wself, Wfwd, Wbwd, Wbig);
  bpre_kernel<<<L, 128, 0, stream>>>(Wcomb, bself, bcomb, biasc, L);

  // 1. CSR build (edges constant within a call)
  hipMemsetAsync(counts, 0, (size_t)N * 4, stream);
  hist_kernel<<<(E + 255) / 256, 256, 0, stream>>>(ei + E, counts, E);
  int nb = (N + 1023) / 1024;
  scan1_kernel<<<nb, 256, 0, stream>>>(counts, ex, partials, N);
  scan2_kernel<<<1, 256, 0, stream>>>(partials, nb);
  scan3_kernel<<<(N + 255) / 256, 256, 0, stream>>>(ex, partials, indptr, N, E);
  hipMemcpyAsync(cursor, indptr, (size_t)N * 4, hipMemcpyDeviceToDevice, stream);
  scatter_kernel<<<(E + 255) / 256, 256, 0, stream>>>(ei, cursor, ssrc, E);

  // 2. embedding: hb = relu(x @ Wemb^T + bemb), fused layer-0 scores
  embed_gemm<true><<<gb, 256, 0, stream>>>(x, Wemb_b, bemb, Wscore, bscore,
                                           hb16, scores, N);

  // 3. layers: aggr -> staged GEMM+LN+residual(+next scores)
  for (int l = 0; l < L; ++l) {
    aggr_kernel<<<(N + 3) / 4, 256, 0, stream>>>(indptr, ssrc, scores, hb16, uv, N);
    if (l < L - 1) {
      layer_gemm<true><<<gb, 256, 0, stream>>>(
          hb16, uv, Wbig + (size_t)l * 128 * 384, biasc + (size_t)l * 128,
          gamma + (size_t)l * 128, beta + (size_t)l * 128,
          Wscore + (size_t)(l + 1) * 128, bscore + (l + 1), hb16, scores, N);
    } else {
      layer_gemm<false><<<gb, 256, 0, stream>>>(
          hb16, uv, Wbig + (size_t)l * 128 * 384, biasc + (size_t)l * 128,
          gamma + (size_t)l * 128, beta + (size_t)l * 128,
          nullptr, nullptr, hb16, scores, N);
    }
  }

  // 4. global mean pool (two-stage, no atomics)
  pool_stage_kernel<<<dim3(G, PS), 128, 0, stream>>>(hb16, batch, pool_p, N);
  pool_final_kernel<<<(G * 128 + 255) / 256, 256, 0, stream>>>(pool_p, batch, out, N, G);
}

// Round 11
// 425.442 us; speedup vs baseline: 1.3380x; 1.0177x over previous
//
#include <hip/hip_runtime.h>
#include <math.h>

#define EPS 1e-5f
#define PS 8  // pool slices per group
#define SW(row) (((row) & 7) << 4)   // XOR swizzle, 16B granularity

typedef __attribute__((ext_vector_type(8))) short short8;
typedef __attribute__((ext_vector_type(4))) float f32x4;

__device__ __forceinline__ float bf2f(unsigned short u) {
  union { unsigned i; float f; } c; c.i = ((unsigned)u) << 16; return c.f;
}
__device__ __forceinline__ float bflo(unsigned u) {
  union { unsigned i; float f; } c; c.i = u << 16; return c.f;
}
__device__ __forceinline__ float bfhi(unsigned u) {
  union { unsigned i; float f; } c; c.i = u & 0xFFFF0000u; return c.f;
}
__device__ __forceinline__ unsigned short f2bf(float f) {
  union { float f; unsigned i; } c; c.f = f;
  unsigned r = c.i + 0x7FFF + ((c.i >> 16) & 1);
  return (unsigned short)(r >> 16);
}

// ---------------------------------------------------------------------------
// Embed GEMM (K=128), LDS-staged: hb = relu(x_f32 @ W^T + bias) bf16 (+score).
// BM=64, 4 waves 2x2 (wave tile 32x64). A read fp32 + converted in-register
// during staging; W bf16. XOR-swizzled LDS; ds_read_b128 conflict-free.
// ---------------------------------------------------------------------------
template <bool SCORE>
__global__ __launch_bounds__(256, 2) void embed_gemm(
    const float* __restrict__ X,      // x [M][128] fp32
    const ushort* __restrict__ W,     // [128][128] bf16
    const float* __restrict__ bias,
    const float* __restrict__ Wsc, const float* __restrict__ bsc,
    ushort* __restrict__ hb, float* __restrict__ scores, int M) {
  __shared__ __align__(16) ushort As[64 * 128];    // 16 KB, row 256 B
  __shared__ __align__(16) ushort Ws[128 * 128];   // 32 KB, row 256 B
  __shared__ float lds3[64][2];

  const int t = threadIdx.x;
  const int lane = t & 63;
  const int w = t >> 6;
  const int wm = w >> 1, wn = w & 1;
  const int m0 = blockIdx.x * 64;
  const int l15 = lane & 15, l16 = lane >> 4;

  // stage: A 1024 chunks (4/thread, fp32->bf16), W 2048 chunks (8/thread)
  short8 ar[4], wr_[8];
#pragma unroll
  for (int it = 0; it < 4; ++it) {
    int chunk = it * 256 + t;
    int row = chunk >> 4;           // 16 chunks per 256B row
    int b16 = chunk & 15;
    int grow = m0 + row; if (grow >= M) grow = M - 1;
    const float* xr = X + (size_t)grow * 128 + b16 * 8;
    float4 f0 = *(const float4*)xr;
    float4 f1 = *(const float4*)(xr + 4);
    short8 v;
    v[0] = (short)f2bf(f0.x); v[1] = (short)f2bf(f0.y);
    v[2] = (short)f2bf(f0.z); v[3] = (short)f2bf(f0.w);
    v[4] = (short)f2bf(f1.x); v[5] = (short)f2bf(f1.y);
    v[6] = (short)f2bf(f1.z); v[7] = (short)f2bf(f1.w);
    ar[it] = v;
  }
#pragma unroll
  for (int it = 0; it < 8; ++it) {
    int chunk = it * 256 + t;
    int row = chunk >> 4;
    int b16 = chunk & 15;
    wr_[it] = *(const short8*)(W + (size_t)row * 128 + b16 * 8);
  }
#pragma unroll
  for (int it = 0; it < 4; ++it) {
    int chunk = it * 256 + t;
    int row = chunk >> 4, b = (chunk & 15) * 16;
    *(short8*)((char*)As + row * 256 + (b ^ SW(row))) = ar[it];
  }
#pragma unroll
  for (int it = 0; it < 8; ++it) {
    int chunk = it * 256 + t;
    int row = chunk >> 4, b = (chunk & 15) * 16;
    *(short8*)((char*)Ws + row * 256 + (b ^ SW(row))) = wr_[it];
  }
  __syncthreads();

  f32x4 acc[2][4];
#pragma unroll
  for (int i = 0; i < 2; ++i)
#pragma unroll
    for (int j = 0; j < 4; ++j) acc[i][j] = (f32x4){0.f, 0.f, 0.f, 0.f};

#pragma unroll
  for (int kk = 0; kk < 4; ++kk) {
    int cb = kk * 64 + l16 * 16;
    short8 a[2], b[4];
#pragma unroll
    for (int i = 0; i < 2; ++i) {
      int row = wm * 32 + i * 16 + l15;
      a[i] = *(const short8*)((const char*)As + row * 256 + (cb ^ SW(row)));
    }
#pragma unroll
    for (int j = 0; j < 4; ++j) {
      int row = wn * 64 + j * 16 + l15;
      b[j] = *(const short8*)((const char*)Ws + row * 256 + (cb ^ SW(row)));
    }
#pragma unroll
    for (int i = 0; i < 2; ++i)
#pragma unroll
      for (int j = 0; j < 4; ++j)
        acc[i][j] = __builtin_amdgcn_mfma_f32_16x16x32_bf16(a[i], b[j], acc[i][j], 0, 0, 0);
  }

  // epilogue: relu + hb store + optional score
#pragma unroll
  for (int i = 0; i < 2; ++i)
#pragma unroll
    for (int r = 0; r < 4; ++r) {
      int row = m0 + wm * 32 + i * 16 + l16 * 4 + r;
      bool valid = row < M;
      float psc = 0.f;
#pragma unroll
      for (int j = 0; j < 4; ++j) {
        int colw = wn * 64 + j * 16 + l15;
        float v = acc[i][j][r] + bias[colw];
        v = fmaxf(v, 0.f);
        if (valid) hb[(size_t)row * 128 + colw] = f2bf(v);
        if (SCORE) psc += v * Wsc[colw];
      }
      if (SCORE) {
#pragma unroll
        for (int mm = 1; mm <= 8; mm <<= 1) psc += __shfl_xor(psc, mm, 64);
        if (l15 == 0) lds3[wm * 32 + i * 16 + l16 * 4 + r][wn] = psc;
      }
    }
  if (SCORE) {
    __syncthreads();
    if (wn == 0 && l15 == 0) {
#pragma unroll
      for (int i = 0; i < 2; ++i)
#pragma unroll
        for (int r = 0; r < 4; ++r) {
          int rl = wm * 32 + i * 16 + l16 * 4 + r;
          int row = blockIdx.x * 64 + rl;
          if (row < M) scores[row] = lds3[rl][0] + lds3[rl][1] + bsc[0];
        }
    }
  }
}

// ---------------------------------------------------------------------------
// Layer GEMM (K=384), LDS-staged in two K-halves of 192:
// z = [hb | uv] @ Wbig^T + biasc; LayerNorm; relu; += hb residual (bf16 state);
// writes hb (+ next-layer score). BM=64, 4 waves 2x2 (wave tile 32x64).
// LDS: As 24 KB + Ws 48 KB (XOR swizzle) = 72 KB -> 2 blocks/CU.
// ---------------------------------------------------------------------------
template <bool SCORE>
__global__ __launch_bounds__(256, 2) void layer_gemm(
    const ushort* __restrict__ A0,    // hb [M][128]
    const ushort* __restrict__ A1,    // uv [M][256]
    const ushort* __restrict__ W,     // Wbig [128][384]
    const float* __restrict__ bias,
    const float* __restrict__ gamma, const float* __restrict__ beta,
    const float* __restrict__ Wsc, const float* __restrict__ bsc,
    ushort* __restrict__ hb, float* __restrict__ scores, int M) {
  __shared__ __align__(16) ushort As[64 * 192];    // 24 KB, row 384 B
  __shared__ __align__(16) ushort Ws[128 * 192];   // 48 KB, row 384 B
  __shared__ float lds1[64][2];
  __shared__ float lds2[64][2];
  __shared__ float lds3[64][2];

  const int t = threadIdx.x;
  const int lane = t & 63;
  const int w = t >> 6;
  const int wm = w >> 1, wn = w & 1;
  const int m0 = blockIdx.x * 64;
  const int l15 = lane & 15, l16 = lane >> 4;

  f32x4 acc[2][4];
#pragma unroll
  for (int i = 0; i < 2; ++i)
#pragma unroll
    for (int j = 0; j < 4; ++j) acc[i][j] = (f32x4){0.f, 0.f, 0.f, 0.f};

#pragma unroll
  for (int hf = 0; hf < 2; ++hf) {
    // ---- bulk load to regs (independent burst; hides latency) ----
    short8 ar[6], wr_[12];
#pragma unroll
    for (int it = 0; it < 6; ++it) {
      int chunk = it * 256 + t;        // [0,1536): 64 rows x 24 chunks
      int row = chunk / 24;
      int b16 = chunk % 24;
      int ec = hf * 192 + b16 * 8;     // combined element col
      int grow = m0 + row; if (grow >= M) grow = M - 1;
      const ushort* src = (ec < 128) ? (A0 + (size_t)grow * 128 + ec)
                                     : (A1 + (size_t)grow * 256 + (ec - 128));
      ar[it] = *(const short8*)src;
    }
#pragma unroll
    for (int it = 0; it < 12; ++it) {
      int chunk = it * 256 + t;        // [0,3072): 128 rows x 24 chunks
      int row = chunk / 24;
      int b16 = chunk % 24;
      wr_[it] = *(const short8*)(W + (size_t)row * 384 + hf * 192 + b16 * 8);
    }
    __syncthreads();  // previous half's readers done before overwrite
#pragma unroll
    for (int it = 0; it < 6; ++it) {
      int chunk = it * 256 + t;
      int row = chunk / 24, b = (chunk % 24) * 16;
      *(short8*)((char*)As + row * 384 + (b ^ SW(row))) = ar[it];
    }
#pragma unroll
    for (int it = 0; it < 12; ++it) {
      int chunk = it * 256 + t;
      int row = chunk / 24, b = (chunk % 24) * 16;
      *(short8*)((char*)Ws + row * 384 + (b ^ SW(row))) = wr_[it];
    }
    __syncthreads();
    // ---- compute 6 ksteps ----
#pragma unroll
    for (int kk = 0; kk < 6; ++kk) {
      int cb = kk * 64 + l16 * 16;
      short8 a[2], b[4];
#pragma unroll
      for (int i = 0; i < 2; ++i) {
        int row = wm * 32 + i * 16 + l15;
        a[i] = *(const short8*)((const char*)As + row * 384 + (cb ^ SW(row)));
      }
#pragma unroll
      for (int j = 0; j < 4; ++j) {
        int row = wn * 64 + j * 16 + l15;
        b[j] = *(const short8*)((const char*)Ws + row * 384 + (cb ^ SW(row)));
      }
#pragma unroll
      for (int i = 0; i < 2; ++i)
#pragma unroll
        for (int j = 0; j < 4; ++j)
          acc[i][j] = __builtin_amdgcn_mfma_f32_16x16x32_bf16(a[i], b[j], acc[i][j], 0, 0, 0);
    }
  }

  // ---- epilogue: bias + LN stats (pass 1) ----
#pragma unroll
  for (int i = 0; i < 2; ++i)
#pragma unroll
    for (int r = 0; r < 4; ++r) {
      float p1 = 0.f, p2 = 0.f;
#pragma unroll
      for (int j = 0; j < 4; ++j) {
        int colw = wn * 64 + j * 16 + l15;
        float v = acc[i][j][r] + bias[colw];
        acc[i][j][r] = v;
        p1 += v;
        p2 += v * v;
      }
#pragma unroll
      for (int mm = 1; mm <= 8; mm <<= 1) {
        p1 += __shfl_xor(p1, mm, 64);
        p2 += __shfl_xor(p2, mm, 64);
      }
      if (l15 == 0) {
        int rl = wm * 32 + i * 16 + l16 * 4 + r;
        lds1[rl][wn] = p1;
        lds2[rl][wn] = p2;
      }
    }
  __syncthreads();
  // ---- pass 2: normalize + relu + residual(bf16, L2-hot) + store ----
#pragma unroll
  for (int i = 0; i < 2; ++i)
#pragma unroll
    for (int r = 0; r < 4; ++r) {
      int rl = wm * 32 + i * 16 + l16 * 4 + r;
      int row = m0 + rl;
      bool valid = row < M;
      float s1 = lds1[rl][0] + lds1[rl][1];
      float s2 = lds2[rl][0] + lds2[rl][1];
      float mu = s1 * (1.f / 128.f);
      float var = s2 * (1.f / 128.f) - mu * mu;
      float rs = rsqrtf(var + EPS);
      float psc = 0.f;
#pragma unroll
      for (int j = 0; j < 4; ++j) {
        int colw = wn * 64 + j * 16 + l15;
        float v = acc[i][j][r];
        float o = (v - mu) * rs * gamma[colw] + beta[colw];
        o = fmaxf(o, 0.f);
        float res = o;
        if (valid) {
          res = o + bf2f(hb[(size_t)row * 128 + colw]);
          hb[(size_t)row * 128 + colw] = f2bf(res);
        }
        if (SCORE) psc += res * Wsc[colw];
      }
      if (SCORE) {
#pragma unroll
        for (int mm = 1; mm <= 8; mm <<= 1) psc += __shfl_xor(psc, mm, 64);
        if (l15 == 0) lds3[rl][wn] = psc;
      }
    }
  if (SCORE) {
    __syncthreads();
    if (wn == 0 && l15 == 0) {
#pragma unroll
      for (int i = 0; i < 2; ++i)
#pragma unroll
        for (int r = 0; r < 4; ++r) {
          int rl = wm * 32 + i * 16 + l16 * 4 + r;
          int row = m0 + rl;
          if (row < M) scores[row] = lds3[rl][0] + lds3[rl][1] + bsc[0];
        }
    }
  }
}

// ---------------------------------------------------------------------------
// Weight precompute: Wbig[l][:, p*128:(p+1)*128] = Wcomb[l][:,p-part] @ Wp[l]
// ---------------------------------------------------------------------------
__global__ __launch_bounds__(256) void wpre_kernel(
    const float* __restrict__ Wcomb, const float* __restrict__ Wself,
    const float* __restrict__ Wfwd, const float* __restrict__ Wbwd,
    ushort* __restrict__ Wbig) {
  const int l = blockIdx.x / 3, p = blockIdx.x % 3;
  const float* Wc = Wcomb + (size_t)l * 128 * 384;
  const float* Wp = (p == 0 ? Wself : (p == 1 ? Wfwd : Wbwd)) + (size_t)l * 128 * 128;
  __shared__ float Bs[128][132];
  const int t = threadIdx.x;
  for (int i = t; i < 16384; i += 256) Bs[i >> 7][i & 127] = Wp[i];
  __syncthreads();
  const int r = t >> 1;
  const int c0 = (t & 1) * 64;
  float acc[64];
#pragma unroll
  for (int c = 0; c < 64; ++c) acc[c] = 0.f;
  for (int k = 0; k < 128; ++k) {
    float a = Wc[(size_t)r * 384 + p * 128 + k];
#pragma unroll
    for (int c4 = 0; c4 < 16; ++c4) {
      float4 b4 = *(const float4*)&Bs[k][c0 + c4 * 4];
      acc[c4 * 4 + 0] = fmaf(a, b4.x, acc[c4 * 4 + 0]);
      acc[c4 * 4 + 1] = fmaf(a, b4.y, acc[c4 * 4 + 1]);
      acc[c4 * 4 + 2] = fmaf(a, b4.z, acc[c4 * 4 + 2]);
      acc[c4 * 4 + 3] = fmaf(a, b4.w, acc[c4 * 4 + 3]);
    }
  }
  ushort* o = Wbig + (size_t)l * 128 * 384 + (size_t)r * 384 + p * 128 + c0;
#pragma unroll
  for (int c = 0; c < 64; ++c) o[c] = f2bf(acc[c]);
}

// bias_c[l][c] = bcomb[l][c] + sum_k Wcomb[l][c][k] * bself[l][k]
__global__ void bpre_kernel(const float* __restrict__ Wcomb, const float* __restrict__ bself,
                            const float* __restrict__ bcomb, float* __restrict__ biasc, int L) {
  int idx = blockIdx.x * 128 + threadIdx.x;
  if (idx >= L * 128) return;
  int l = idx >> 7;
  const float* Wc = Wcomb + (size_t)l * 128 * 384 + (size_t)(idx & 127) * 384;
  const float* bs = bself + (size_t)l * 128;
  float acc = bcomb[idx];
  for (int k = 0; k < 128; ++k) acc = fmaf(Wc[k], bs[k], acc);
  biasc[idx] = acc;
}

// fp32 -> bf16 (n4 float4 groups)
__global__ void f2b_kernel(const float* __restrict__ in, ushort* __restrict__ out, int n4) {
  int i = blockIdx.x * 256 + threadIdx.x;
  if (i < n4) {
    float4 v = ((const float4*)in)[i];
    ushort4 o;
    o.x = f2bf(v.x); o.y = f2bf(v.y); o.z = f2bf(v.z); o.w = f2bf(v.w);
    ((ushort4*)out)[i] = o;
  }
}

// ---------------------------------------------------------------------------
// CSR build: histogram -> scan -> scatter (counting sort by dst)
// ---------------------------------------------------------------------------
__global__ void hist_kernel(const int* __restrict__ dst, int* __restrict__ counts, int E) {
  int e = blockIdx.x * 256 + threadIdx.x;
  if (e < E) atomicAdd(&counts[dst[e]], 1);
}

__global__ __launch_bounds__(256) void scan1_kernel(
    const int* __restrict__ c, int* __restrict__ ex, int* __restrict__ partials, int n) {
  __shared__ int sd[256];
  int t = threadIdx.x, b = blockIdx.x;
  int base = b * 1024 + t * 4;
  int v0 = (base + 0 < n) ? c[base + 0] : 0;
  int v1 = (base + 1 < n) ? c[base + 1] : 0;
  int v2 = (base + 2 < n) ? c[base + 2] : 0;
  int v3 = (base + 3 < n) ? c[base + 3] : 0;
  int tot = v0 + v1 + v2 + v3;
  sd[t] = tot;
  __syncthreads();
  for (int off = 1; off < 256; off <<= 1) {
    int x = (t >= off) ? sd[t - off] : 0;
    __syncthreads();
    sd[t] += x;
    __syncthreads();
  }
  int p = sd[t] - tot;
  if (base + 0 < n) ex[base + 0] = p;
  if (base + 1 < n) ex[base + 1] = p + v0;
  if (base + 2 < n) ex[base + 2] = p + v0 + v1;
  if (base + 3 < n) ex[base + 3] = p + v0 + v1 + v2;
  if (t == 255) partials[b] = sd[255];
}

__global__ __launch_bounds__(256) void scan2_kernel(int* __restrict__ partials, int nb) {
  __shared__ int sd[256];
  int t = threadIdx.x;
  int v = (t < nb) ? partials[t] : 0;
  sd[t] = v;
  __syncthreads();
  for (int off = 1; off < 256; off <<= 1) {
    int x = (t >= off) ? sd[t - off] : 0;
    __syncthreads();
    sd[t] += x;
    __syncthreads();
  }
  if (t < nb) partials[t] = sd[t] - v;
}

__global__ void scan3_kernel(const int* __restrict__ ex, const int* __restrict__ partials,
                             int* __restrict__ indptr, int* __restrict__ cursor,
                             int n, int E) {
  int i = blockIdx.x * 256 + threadIdx.x;
  if (i < n) {
    int v = ex[i] + partials[i >> 10];
    indptr[i] = v;
    cursor[i] = v;
  }
  if (i == 0) indptr[n] = E;
}

__global__ void scatter_kernel(const int* __restrict__ ei, int* __restrict__ cursor,
                               int* __restrict__ ssrc, int E) {
  int e = blockIdx.x * 256 + threadIdx.x;
  if (e >= E) return;
  int s = ei[e];
  int d = ei[E + e];
  int pos = atomicAdd(&cursor[d], 1);
  ssrc[pos] = s;
}

// ---------------------------------------------------------------------------
// Edge aggregation: 4 nodes/wave (16-lane quarters). Each lane reads 16B
// (uint4) -> 16 lanes cover a 256B row. Per quarter: prefetch up to 16
// edges' (src, alpha), then x4-unrolled row loads -> up to 16 independent
// loads in flight per wave. u = sum al*h[s]; v = sum h[s] - u.
// ---------------------------------------------------------------------------
__global__ __launch_bounds__(256) void aggr_kernel(
    const int* __restrict__ indptr, const int* __restrict__ ssrc,
    const float* __restrict__ scores, const ushort* __restrict__ hb,
    ushort* __restrict__ uv, int Nn) {
  const int t = threadIdx.x;
  const int lane = t & 63;
  const int q = lane & 15;           // lane within quarter
  const int qbase = lane & 48;       // quarter start lane
  const int node = blockIdx.x * 16 + (t >> 6) * 4 + (lane >> 4);
  if (node >= Nn) return;
  int beg = indptr[node], end = indptr[node + 1];
  float si = scores[node];
  float u0 = 0.f, u1 = 0.f, u2 = 0.f, u3 = 0.f;
  float u4 = 0.f, u5 = 0.f, u6 = 0.f, u7 = 0.f;
  float t0 = 0.f, t1 = 0.f, t2 = 0.f, t3 = 0.f;
  float t4 = 0.f, t5 = 0.f, t6 = 0.f, t7 = 0.f;

  for (int ebase = beg; ebase < end; ebase += 16) {
    int cnt = min(16, end - ebase);
    int sv = 0;
    float al = 0.f;
    if (q < cnt) {
      sv = ssrc[ebase + q];
      al = 1.f / (1.f + __expf(si - scores[sv]));  // sigmoid(scores[s]-si)
    }
    int e = 0;
    for (; e + 4 <= cnt; e += 4) {
      int s0 = __shfl(sv, qbase + e, 64),     s1 = __shfl(sv, qbase + e + 1, 64);
      int s2 = __shfl(sv, qbase + e + 2, 64), s3 = __shfl(sv, qbase + e + 3, 64);
      float a0 = __shfl(al, qbase + e, 64),     a1 = __shfl(al, qbase + e + 1, 64);
      float a2 = __shfl(al, qbase + e + 2, 64), a3 = __shfl(al, qbase + e + 3, 64);
      uint4 v0 = *(const uint4*)(hb + (size_t)s0 * 128 + q * 8);
      uint4 v1 = *(const uint4*)(hb + (size_t)s1 * 128 + q * 8);
      uint4 v2 = *(const uint4*)(hb + (size_t)s2 * 128 + q * 8);
      uint4 v3 = *(const uint4*)(hb + (size_t)s3 * 128 + q * 8);
      float f;
#define ACC8(V, A)                                              \
      f = bflo(V.x); u0 = fmaf(A, f, u0); t0 += f;              \
      f = bfhi(V.x); u1 = fmaf(A, f, u1); t1 += f;              \
      f = bflo(V.y); u2 = fmaf(A, f, u2); t2 += f;              \
      f = bfhi(V.y); u3 = fmaf(A, f, u3); t3 += f;              \
      f = bflo(V.z); u4 = fmaf(A, f, u4); t4 += f;              \
      f = bfhi(V.z); u5 = fmaf(A, f, u5); t5 += f;              \
      f = bflo(V.w); u6 = fmaf(A, f, u6); t6 += f;              \
      f = bfhi(V.w); u7 = fmaf(A, f, u7); t7 += f;
      ACC8(v0, a0)
      ACC8(v1, a1)
      ACC8(v2, a2)
      ACC8(v3, a3)
    }
    for (; e < cnt; ++e) {
      int s_e = __shfl(sv, qbase + e, 64);
      float a_e = __shfl(al, qbase + e, 64);
      uint4 vv = *(const uint4*)(hb + (size_t)s_e * 128 + q * 8);
      float f;
      ACC8(vv, a_e)
#undef ACC8
    }
  }
  uint4 pu, pv;
  pu.x = (unsigned)f2bf(u0) | ((unsigned)f2bf(u1) << 16);
  pu.y = (unsigned)f2bf(u2) | ((unsigned)f2bf(u3) << 16);
  pu.z = (unsigned)f2bf(u4) | ((unsigned)f2bf(u5) << 16);
  pu.w = (unsigned)f2bf(u6) | ((unsigned)f2bf(u7) << 16);
  pv.x = (unsigned)f2bf(t0 - u0) | ((unsigned)f2bf(t1 - u1) << 16);
  pv.y = (unsigned)f2bf(t2 - u2) | ((unsigned)f2bf(t3 - u3) << 16);
  pv.z = (unsigned)f2bf(t4 - u4) | ((unsigned)f2bf(t5 - u5) << 16);
  pv.w = (unsigned)f2bf(t6 - u6) | ((unsigned)f2bf(t7 - u7) << 16);
  *(uint4*)(uv + (size_t)node * 256 + q * 8) = pu;
  *(uint4*)(uv + (size_t)node * 256 + 128 + q * 8) = pv;
}

// ---------------------------------------------------------------------------
// Global mean pool over hb (bf16 state; batch sorted): two-stage, no atomics.
// ---------------------------------------------------------------------------
__global__ __launch_bounds__(128) void pool_stage_kernel(
    const ushort* __restrict__ hb, const int* __restrict__ batch,
    float* __restrict__ partial, int M) {
  int g = blockIdx.x, s = blockIdx.y, d = threadIdx.x;
  int lo = 0, hi = M;
  while (lo < hi) { int mid = (lo + hi) >> 1; if (batch[mid] < g) lo = mid + 1; else hi = mid; }
  int b0 = lo;
  hi = M;
  while (lo < hi) { int mid = (lo + hi) >> 1; if (batch[mid] <= g) lo = mid + 1; else hi = mid; }
  int b1 = lo;
  int len = b1 - b0;
  int chunk = (len + PS - 1) / PS;
  int r0 = b0 + s * chunk;
  int r1 = min(b1, r0 + chunk);
  float acc = 0.f;
  for (int i = r0; i < r1; ++i) acc += bf2f(hb[(size_t)i * 128 + d]);
  partial[((size_t)g * PS + s) * 128 + d] = acc;
}

__global__ void pool_final_kernel(const float* __restrict__ partial,
                                  const int* __restrict__ batch,
                                  float* __restrict__ out, int M, int G) {
  int idx = blockIdx.x * 256 + threadIdx.x;
  if (idx >= G * 128) return;
  int g = idx >> 7, d = idx & 127;
  float acc = 0.f;
#pragma unroll
  for (int s = 0; s < PS; ++s) acc += partial[((size_t)g * PS + s) * 128 + d];
  int lo = 0, hi = M;
  while (lo < hi) { int mid = (lo + hi) >> 1; if (batch[mid] < g) lo = mid + 1; else hi = mid; }
  int b0 = lo;
  hi = M;
  while (lo < hi) { int mid = (lo + hi) >> 1; if (batch[mid] <= g) lo = mid + 1; else hi = mid; }
  int c = lo - b0;
  out[idx] = acc / (float)(c > 0 ? c : 1);
}

// ---------------------------------------------------------------------------
extern "C" void kernel_launch(void* const* d_in, const int* in_sizes, int n_in,
                              void* d_out, int out_size, void* d_ws, size_t ws_size,
                              hipStream_t stream) {
  const float* x      = (const float*)d_in[0];
  const int*   ei     = (const int*)d_in[1];
  const int*   batch  = (const int*)d_in[2];
  const float* Wemb   = (const float*)d_in[3];
  const float* bemb   = (const float*)d_in[4];
  const float* Wscore = (const float*)d_in[5];
  const float* bscore = (const float*)d_in[6];
  const float* Wfwd   = (const float*)d_in[7];
  const float* Wbwd   = (const float*)d_in[8];
  const float* Wself  = (const float*)d_in[9];
  const float* bself  = (const float*)d_in[10];
  const float* Wcomb  = (const float*)d_in[11];
  const float* bcomb  = (const float*)d_in[12];
  const float* gamma  = (const float*)d_in[13];
  const float* beta   = (const float*)d_in[14];

  const int N = in_sizes[0] / 128;
  const int E = in_sizes[1] / 2;
  const int L = in_sizes[5] / 128;
  const int G = out_size / 128;
  float* out = (float*)d_out;

  char* p = (char*)d_ws;
  auto alloc = [&](size_t bytes) -> char* {
    char* r = p;
    p += (bytes + 255) & ~(size_t)255;
    return r;
  };
  ushort* hb16   = (ushort*)alloc((size_t)N * 128 * 2);   // bf16 state (only state)
  ushort* uv     = (ushort*)alloc((size_t)N * 256 * 2);   // [u | v] bf16
  float*  scores = (float*)alloc((size_t)N * 4);
  ushort* Wemb_b = (ushort*)alloc(16384 * 2);
  ushort* Wbig   = (ushort*)alloc((size_t)L * 128 * 384 * 2);
  float*  biasc  = (float*)alloc((size_t)L * 128 * 4);
  int* counts    = (int*)alloc((size_t)N * 4);
  int* ex        = (int*)alloc((size_t)N * 4);
  int* partials  = (int*)alloc(1024);
  int* indptr    = (int*)alloc((size_t)(N + 1) * 4);
  int* cursor    = (int*)alloc((size_t)N * 4);
  int* ssrc      = (int*)alloc((size_t)E * 4);
  float* pool_p  = (float*)alloc((size_t)G * PS * 128 * 4);

  const int gb = (N + 63) / 64;

  // 0. precompute: conversions + combined weights
  f2b_kernel<<<16, 256, 0, stream>>>(Wemb, Wemb_b, 4096);
  wpre_kernel<<<3 * L, 256, 0, stream>>>(Wcomb, Wself, Wfwd, Wbwd, Wbig);
  bpre_kernel<<<L, 128, 0, stream>>>(Wcomb, bself, bcomb, biasc, L);

  // 1. CSR build (edges constant within a call)
  hipMemsetAsync(counts, 0, (size_t)N * 4, stream);
  hist_kernel<<<(E + 255) / 256, 256, 0, stream>>>(ei + E, counts, E);
  int nb = (N + 1023) / 1024;
  scan1_kernel<<<nb, 256, 0, stream>>>(counts, ex, partials, N);
  scan2_kernel<<<1, 256, 0, stream>>>(partials, nb);
  scan3_kernel<<<(N + 255) / 256, 256, 0, stream>>>(ex, partials, indptr, cursor, N, E);
  scatter_kernel<<<(E + 255) / 256, 256, 0, stream>>>(ei, cursor, ssrc, E);

  // 2. embedding: hb = relu(x @ Wemb^T + bemb), fused layer-0 scores
  embed_gemm<true><<<gb, 256, 0, stream>>>(x, Wemb_b, bemb, Wscore, bscore,
                                           hb16, scores, N);

  // 3. layers: aggr -> staged GEMM+LN+residual(+next scores)
  for (int l = 0; l < L; ++l) {
    aggr_kernel<<<(N + 15) / 16, 256, 0, stream>>>(indptr, ssrc, scores, hb16, uv, N);
    if (l < L - 1) {
      layer_gemm<true><<<gb, 256, 0, stream>>>(
          hb16, uv, Wbig + (size_t)l * 128 * 384, biasc + (size_t)l * 128,
          gamma + (size_t)l * 128, beta + (size_t)l * 128,
          Wscore + (size_t)(l + 1) * 128, bscore + (l + 1), hb16, scores, N);
    } else {
      layer_gemm<false><<<gb, 256, 0, stream>>>(
          hb16, uv, Wbig + (size_t)l * 128 * 384, biasc + (size_t)l * 128,
          gamma + (size_t)l * 128, beta + (size_t)l * 128,
          nullptr, nullptr, hb16, scores, N);
    }
  }

  // 4. global mean pool (two-stage, no atomics)
  pool_stage_kernel<<<dim3(G, PS), 128, 0, stream>>>(hb16, batch, pool_p, N);
  pool_final_kernel<<<(G * 128 + 255) / 256, 256, 0, stream>>>(pool_p, batch, out, N, G);
}